// Round 13
// baseline (361.224 us; speedup 1.0000x reference)
//
#include <hip/hip_runtime.h>
#include <math.h>

#define LATN 512
#define DN 256
#define DKN 128
#define TTOT 4096   // B*LAT
#define NEXP 10
#define DFFN 1024

using bf16x8 = __attribute__((ext_vector_type(8))) short;
using f32x4  = __attribute__((ext_vector_type(4))) float;

__device__ __forceinline__ float dot4(float4 a, float4 b) {
    return a.x*b.x + a.y*b.y + a.z*b.z + a.w*b.w;
}

__device__ __forceinline__ unsigned short f2bf(float f) {
    union { float f; unsigned int u; } v; v.f = f;
    unsigned int u = v.u + 0x7FFFu + ((v.u >> 16) & 1u);
    return (unsigned short)(u >> 16);
}

__device__ __forceinline__ float wave_sum(float x) {
    #pragma unroll
    for (int off = 32; off; off >>= 1) x += __shfl_xor(x, off, 64);
    return x;
}

// ---------------- zero init (padded counters) ----------------
__global__ void zero_kernel(float* rprob_p, int* ec_p) {
    int i = threadIdx.x;
    if (i < 320) { rprob_p[i] = 0.f; ec_p[i] = 0; }
}

// ---------------- tokenizer: wave-per-token, shfl-only LN ----------------
__global__ __launch_bounds__(256)
void tokenizer_kernel(const float* __restrict__ x, const float* __restrict__ cw,
                      const float* __restrict__ cb, const float* __restrict__ pe,
                      const float* __restrict__ g, const float* __restrict__ bb,
                      float* __restrict__ z) {
    int tid = threadIdx.x;
    int w = tid >> 6, l = tid & 63;
    int t = blockIdx.x*4 + w;
    int lt = t & (LATN - 1);
    int b = t >> 9;
    const float* xb = x + (size_t)b * 1024;
    int p0 = 2 * lt;
    float xv[6];
    #pragma unroll
    for (int i = 0; i < 6; ++i) {
        int p = min(max(p0 - 2 + i, 0), 1023);
        xv[i] = xb[p];
    }
    float v[4]; float s = 0.f, q = 0.f;
    #pragma unroll
    for (int c = 0; c < 4; ++c) {
        int d = l + 64*c;
        float w0 = cw[d*5+0], w1 = cw[d*5+1], w2 = cw[d*5+2], w3 = cw[d*5+3], w4 = cw[d*5+4];
        float bv = cb[d];
        float h0 = bv + w0*xv[0] + w1*xv[1] + w2*xv[2] + w3*xv[3] + w4*xv[4];
        float h1 = bv + w0*xv[1] + w1*xv[2] + w2*xv[3] + w3*xv[4] + w4*xv[5];
        float pool = sqrtf(h0*h0 + h1*h1);
        float val = pool + pe[lt*DN + d];
        v[c] = val; s += val; q += val*val;
    }
    s = wave_sum(s); q = wave_sum(q);
    float mu = s * (1.0f/DN);
    float var = q * (1.0f/DN) - mu*mu;
    float rs = rsqrtf(var + 1e-5f);
    #pragma unroll
    for (int c = 0; c < 4; ++c) {
        int d = l + 64*c;
        z[(size_t)t*DN + d] = (v[c] - mu)*rs*g[d] + bb[d];
    }
}

// ---------------- pack projection weights: fp32 [out,in] -> bf16 B-frag ----------
__global__ void pack_proj(const float* __restrict__ wq, const float* __restrict__ wk,
                          const float* __restrict__ wv, const float* __restrict__ wo,
                          unsigned short* __restrict__ wp) {
    int mat = blockIdx.y;              // 0..7 : layer*4 + {q,k,v,o}
    int l0 = mat >> 2, which = mat & 3;
    const float* base = (which == 0) ? wq : (which == 1) ? wk : (which == 2) ? wv : wo;
    const float* W = base + l0*65536;
    int tid = blockIdx.x*256 + threadIdx.x;   // 0..8191
    int l = tid & 63, kk = (tid >> 6) & 7, nt = tid >> 9;
    const float* src = W + (size_t)(nt*16 + (l&15))*DN + kk*32 + (l>>4)*8;
    unsigned short o[8];
    #pragma unroll
    for (int j = 0; j < 8; ++j) o[j] = f2bf(src[j]);
    *(ulonglong2*)(wp + (size_t)mat*65536 + (size_t)tid*8) = *(ulonglong2*)o;
}

// ---------------- MFMA projection GEMM body. OM: 1=bf16 out, 2=bf16 vT ----------
template<int OM>
__device__ __forceinline__ void proj_body(const float* __restrict__ A,
                                          const unsigned short* __restrict__ wpm,
                                          const float* __restrict__ bias,
                                          void* __restrict__ outp, int t0, float oscale,
                                          unsigned short* ts) {
    int tid = threadIdx.x;
    #pragma unroll
    for (int i = 0; i < 16; ++i) {
        int f4 = i*256 + tid;
        int row = f4 >> 6, c4 = f4 & 63;
        float4 a = *(const float4*)&A[(size_t)(t0+row)*DN + c4*4];
        ushort4 o = { f2bf(a.x), f2bf(a.y), f2bf(a.z), f2bf(a.w) };
        *(ushort4*)&ts[row*264 + c4*4] = o;
    }
    __syncthreads();
    int w = tid >> 6, l = tid & 63;
    f32x4 acc[4][4];
    #pragma unroll
    for (int m = 0; m < 4; ++m)
        #pragma unroll
        for (int n = 0; n < 4; ++n) acc[m][n] = (f32x4){0.f,0.f,0.f,0.f};
    const bf16x8* wv = (const bf16x8*)wpm;
    #pragma unroll
    for (int kk = 0; kk < 8; ++kk) {
        bf16x8 af[4];
        #pragma unroll
        for (int m = 0; m < 4; ++m)
            af[m] = *(const bf16x8*)&ts[(m*16 + (l&15))*264 + kk*32 + (l>>4)*8];
        #pragma unroll
        for (int n = 0; n < 4; ++n) {
            bf16x8 bf = wv[((w*4 + n)*8 + kk)*64 + l];
            #pragma unroll
            for (int m = 0; m < 4; ++m)
                acc[m][n] = __builtin_amdgcn_mfma_f32_16x16x32_bf16(af[m], bf, acc[m][n], 0, 0, 0);
        }
    }
    #pragma unroll
    for (int n = 0; n < 4; ++n) {
        int col = w*64 + n*16 + (l&15);
        float bv2 = bias[col];
        #pragma unroll
        for (int m = 0; m < 4; ++m) {
            #pragma unroll
            for (int r = 0; r < 4; ++r) {
                int row = t0 + m*16 + (l>>4)*4 + r;
                float val = acc[m][n][r] + bv2;
                if (OM == 1)
                    ((unsigned short*)outp)[(size_t)row*DN + col] = f2bf(val * oscale);
                else
                    ((unsigned short*)outp)[(((size_t)(row>>9)*2 + (col>>7))*128 + (col&127))*512 + (row&511)] = f2bf(val);
            }
        }
    }
}

__global__ __launch_bounds__(256)
void proj_qkv(const float* __restrict__ z, const unsigned short* __restrict__ wp,
              const float* __restrict__ bq, const float* __restrict__ bk,
              const float* __restrict__ bv,
              unsigned short* __restrict__ qb, unsigned short* __restrict__ kb,
              unsigned short* __restrict__ vtb) {
    __shared__ unsigned short ts[64*264];
    int mat = blockIdx.y;
    if (mat == 0)      proj_body<1>(z, wp,          bq, qb,  blockIdx.x*64, 0.08838834764831844f, ts);
    else if (mat == 1) proj_body<1>(z, wp + 65536,  bk, kb,  blockIdx.x*64, 1.0f, ts);
    else               proj_body<2>(z, wp + 131072, bv, vtb, blockIdx.x*64, 1.0f, ts);
}

// ---------------- out-proj + residual + LN fused (writes z in place) ------------
__global__ __launch_bounds__(256)
void proj_o_ln(const float* __restrict__ A, const unsigned short* __restrict__ wpm,
               const float* __restrict__ bias, float* __restrict__ z,
               const float* __restrict__ lng, const float* __restrict__ lnb) {
    __shared__ unsigned short ts[64*264];
    __shared__ float wsum[4][64], wsq[4][64];
    int t0 = blockIdx.x * 64;
    int tid = threadIdx.x;
    #pragma unroll
    for (int i = 0; i < 16; ++i) {
        int f4 = i*256 + tid;
        int row = f4 >> 6, c4 = f4 & 63;
        float4 a = *(const float4*)&A[(size_t)(t0+row)*DN + c4*4];
        ushort4 o = { f2bf(a.x), f2bf(a.y), f2bf(a.z), f2bf(a.w) };
        *(ushort4*)&ts[row*264 + c4*4] = o;
    }
    __syncthreads();
    int w = tid >> 6, l = tid & 63, c = l & 15, g = l >> 4;
    f32x4 acc[4][4];
    #pragma unroll
    for (int m = 0; m < 4; ++m)
        #pragma unroll
        for (int n = 0; n < 4; ++n) acc[m][n] = (f32x4){0.f,0.f,0.f,0.f};
    const bf16x8* wv = (const bf16x8*)wpm;
    #pragma unroll
    for (int kk = 0; kk < 8; ++kk) {
        bf16x8 af[4];
        #pragma unroll
        for (int m = 0; m < 4; ++m)
            af[m] = *(const bf16x8*)&ts[(m*16 + c)*264 + kk*32 + g*8];
        #pragma unroll
        for (int n = 0; n < 4; ++n) {
            bf16x8 bf = wv[((w*4 + n)*8 + kk)*64 + l];
            #pragma unroll
            for (int m = 0; m < 4; ++m)
                acc[m][n] = __builtin_amdgcn_mfma_f32_16x16x32_bf16(af[m], bf, acc[m][n], 0, 0, 0);
        }
    }
    float vals[4][4][4];
    float sm[4][4], sq[4][4];
    #pragma unroll
    for (int m = 0; m < 4; ++m)
        #pragma unroll
        for (int r = 0; r < 4; ++r) { sm[m][r] = 0.f; sq[m][r] = 0.f; }
    #pragma unroll
    for (int n = 0; n < 4; ++n) {
        int col = w*64 + n*16 + c;
        float bv2 = bias[col];
        #pragma unroll
        for (int m = 0; m < 4; ++m)
            #pragma unroll
            for (int r = 0; r < 4; ++r) {
                int row = t0 + m*16 + g*4 + r;
                float v = acc[m][n][r] + bv2 + z[(size_t)row*DN + col];
                vals[m][n][r] = v;
                sm[m][r] += v; sq[m][r] += v*v;
            }
    }
    #pragma unroll
    for (int m = 0; m < 4; ++m)
        #pragma unroll
        for (int r = 0; r < 4; ++r) {
            #pragma unroll
            for (int off = 1; off <= 8; off <<= 1) {
                sm[m][r] += __shfl_xor(sm[m][r], off, 64);
                sq[m][r] += __shfl_xor(sq[m][r], off, 64);
            }
        }
    if (c == 0) {
        #pragma unroll
        for (int m = 0; m < 4; ++m)
            #pragma unroll
            for (int r = 0; r < 4; ++r) {
                wsum[w][m*16 + g*4 + r] = sm[m][r];
                wsq[w][m*16 + g*4 + r] = sq[m][r];
            }
    }
    __syncthreads();
    #pragma unroll
    for (int m = 0; m < 4; ++m)
        #pragma unroll
        for (int r = 0; r < 4; ++r) {
            int rl = m*16 + g*4 + r;
            float S = wsum[0][rl] + wsum[1][rl] + wsum[2][rl] + wsum[3][rl];
            float Q = wsq[0][rl] + wsq[1][rl] + wsq[2][rl] + wsq[3][rl];
            float mu = S * (1.0f/DN);
            float var = Q * (1.0f/DN) - mu*mu;
            float rs = rsqrtf(var + 1e-5f);
            int row = t0 + rl;
            #pragma unroll
            for (int n = 0; n < 4; ++n) {
                int col = w*64 + n*16 + c;
                z[(size_t)row*DN + col] = (vals[m][n][r] - mu)*rs*lng[col] + lnb[col];
            }
        }
}

// ---------------- MFMA attention: swapped QK^T (S^T), in-reg softmax, PV via LDS-P
__global__ __launch_bounds__(256)
void attn_mfma(const unsigned short* __restrict__ qb, const unsigned short* __restrict__ kb,
               const unsigned short* __restrict__ vtb, float* __restrict__ a) {
    int blk = blockIdx.x;
    int xcd = blk & 7, idx = blk >> 3;
    int bh = xcd*2 + (idx & 1);        // 2 bh per XCD -> 1 MB L2 working set
    int qt = idx >> 1;
    int b = bh >> 1, h = bh & 1;
    int q0 = qt * 32;
    int tid = threadIdx.x;
    int w = tid >> 6, l = tid & 63;
    int c = l & 15, g = l >> 4;

    __shared__ __align__(16) unsigned short p_lds[32*512];  // [q][key] bf16, XOR-swizzled
    __shared__ float smax[4][2][16];
    __shared__ float ssum[4][2][16];

    bf16x8 qf_[2][4];
    #pragma unroll
    for (int qf = 0; qf < 2; ++qf)
        #pragma unroll
        for (int kk = 0; kk < 4; ++kk)
            qf_[qf][kk] = *(const bf16x8*)&qb[((size_t)(b*LATN + q0 + qf*16 + c))*DN + h*DKN + kk*32 + g*8];

    f32x4 st[8][2];
    #pragma unroll
    for (int f = 0; f < 8; ++f) { st[f][0] = (f32x4){0,0,0,0}; st[f][1] = (f32x4){0,0,0,0}; }
    #pragma unroll
    for (int f = 0; f < 8; ++f) {
        int kbase = w*128 + f*16;
        bf16x8 kf[4];
        #pragma unroll
        for (int kk = 0; kk < 4; ++kk)
            kf[kk] = *(const bf16x8*)&kb[((size_t)(b*LATN + kbase + c))*DN + h*DKN + kk*32 + g*8];
        #pragma unroll
        for (int kk = 0; kk < 4; ++kk) {
            st[f][0] = __builtin_amdgcn_mfma_f32_16x16x32_bf16(kf[kk], qf_[0][kk], st[f][0], 0, 0, 0);
            st[f][1] = __builtin_amdgcn_mfma_f32_16x16x32_bf16(kf[kk], qf_[1][kk], st[f][1], 0, 0, 0);
        }
    }

    float gmax[2], ginv[2];
    #pragma unroll
    for (int qf = 0; qf < 2; ++qf) {
        float m = -1e30f;
        #pragma unroll
        for (int f = 0; f < 8; ++f)
            #pragma unroll
            for (int r = 0; r < 4; ++r) m = fmaxf(m, st[f][qf][r]);
        m = fmaxf(m, __shfl_xor(m, 16, 64));
        m = fmaxf(m, __shfl_xor(m, 32, 64));
        if (l < 16) smax[w][qf][l] = m;
    }
    __syncthreads();
    #pragma unroll
    for (int qf = 0; qf < 2; ++qf)
        gmax[qf] = fmaxf(fmaxf(smax[0][qf][c], smax[1][qf][c]),
                         fmaxf(smax[2][qf][c], smax[3][qf][c]));
    #pragma unroll
    for (int qf = 0; qf < 2; ++qf) {
        float s = 0.f;
        #pragma unroll
        for (int f = 0; f < 8; ++f)
            #pragma unroll
            for (int r = 0; r < 4; ++r) {
                float e = __expf(st[f][qf][r] - gmax[qf]);
                st[f][qf][r] = e; s += e;
            }
        s += __shfl_xor(s, 16, 64);
        s += __shfl_xor(s, 32, 64);
        if (l < 16) ssum[w][qf][l] = s;
    }
    __syncthreads();
    #pragma unroll
    for (int qf = 0; qf < 2; ++qf)
        ginv[qf] = 1.0f / (ssum[0][qf][c] + ssum[1][qf][c] + ssum[2][qf][c] + ssum[3][qf][c]);

    #pragma unroll
    for (int qf = 0; qf < 2; ++qf) {
        int q_ = qf*16 + c;
        int rowb = q_ * 1024;
        int swz = (q_ & 7) << 4;
        float iv = ginv[qf];
        #pragma unroll
        for (int f = 0; f < 8; ++f) {
            unsigned int lo = (unsigned int)f2bf(st[f][qf][0]*iv) |
                              ((unsigned int)f2bf(st[f][qf][1]*iv) << 16);
            unsigned int hi = (unsigned int)f2bf(st[f][qf][2]*iv) |
                              ((unsigned int)f2bf(st[f][qf][3]*iv) << 16);
            int key0 = w*128 + f*16 + g*4;
            *(unsigned long long*)((char*)p_lds + rowb + ((key0*2) ^ swz)) =
                (unsigned long long)lo | ((unsigned long long)hi << 32);
        }
    }
    __syncthreads();

    f32x4 o[2][2];
    o[0][0] = (f32x4){0,0,0,0}; o[0][1] = (f32x4){0,0,0,0};
    o[1][0] = (f32x4){0,0,0,0}; o[1][1] = (f32x4){0,0,0,0};
    #pragma unroll
    for (int kk = 0; kk < 16; ++kk) {
        bf16x8 pb[2];
        #pragma unroll
        for (int qf = 0; qf < 2; ++qf) {
            int q_ = qf*16 + c;
            pb[qf] = *(const bf16x8*)((const char*)p_lds + q_*1024 +
                                      (((kk*32 + g*8)*2) ^ ((q_&7)<<4)));
        }
        bf16x8 va[2];
        #pragma unroll
        for (int m = 0; m < 2; ++m)
            va[m] = *(const bf16x8*)&vtb[((size_t)(bh*128 + w*32 + m*16 + c))*512 + kk*32 + g*8];
        #pragma unroll
        for (int m = 0; m < 2; ++m) {
            o[m][0] = __builtin_amdgcn_mfma_f32_16x16x32_bf16(va[m], pb[0], o[m][0], 0, 0, 0);
            o[m][1] = __builtin_amdgcn_mfma_f32_16x16x32_bf16(va[m], pb[1], o[m][1], 0, 0, 0);
        }
    }
    #pragma unroll
    for (int m = 0; m < 2; ++m)
        #pragma unroll
        for (int qf = 0; qf < 2; ++qf)
            #pragma unroll
            for (int r = 0; r < 4; ++r) {
                int d = w*32 + m*16 + g*4 + r;
                a[((size_t)(b*LATN + q0 + qf*16 + c))*DN + h*DKN + d] = o[m][qf][r];
            }
}

// ---------------- router: 32 tokens/block, block-aggregated padded atomics ----
#define RTOK 32
__global__ __launch_bounds__(512)
void router_kernel(const float* __restrict__ z, const float* __restrict__ rw,
                   const float* __restrict__ rb, float* __restrict__ rmaxv,
                   float* __restrict__ rprob_p, int* __restrict__ ec_p,
                   int* __restrict__ elist) {
    __shared__ float rws[NEXP*DN];
    __shared__ float sprob[NEXP];
    __shared__ int lcnt[NEXP], lbase[NEXP];
    __shared__ int lrank[RTOK];
    __shared__ int lam[RTOK];
    int tid = threadIdx.x;
    for (int i = tid; i < NEXP*DN; i += 512) rws[i] = rw[i];
    if (tid < NEXP) { sprob[tid] = 0.f; lcnt[tid] = 0; }
    __syncthreads();
    int g = tid >> 4, j = tid & 15;
    int t = blockIdx.x * RTOK + g;
    const float4* z4 = (const float4*)&z[(size_t)t*DN + j*16];
    const float4* rws4 = (const float4*)rws;
    float acc[NEXP];
    #pragma unroll
    for (int e = 0; e < NEXP; ++e) acc[e] = 0.f;
    int r0 = (j >> 1) & 3;
    #pragma unroll
    for (int kq = 0; kq < 4; ++kq) {
        int k4 = (kq + r0) & 3;
        float4 zv = z4[k4];
        #pragma unroll
        for (int e = 0; e < NEXP; ++e)
            acc[e] += dot4(zv, rws4[e*64 + j*4 + k4]);
    }
    #pragma unroll
    for (int e = 0; e < NEXP; ++e) {
        acc[e] += __shfl_xor(acc[e], 1, 64);
        acc[e] += __shfl_xor(acc[e], 2, 64);
        acc[e] += __shfl_xor(acc[e], 4, 64);
        acc[e] += __shfl_xor(acc[e], 8, 64);
    }
    if (j == 0) {
        float lg[NEXP];
        float m = acc[0] + rb[0]; int am = 0;
        lg[0] = m;
        #pragma unroll
        for (int e = 1; e < NEXP; ++e) {
            lg[e] = acc[e] + rb[e];
            if (lg[e] > m) { m = lg[e]; am = e; }
        }
        float p[NEXP], s = 0.f;
        #pragma unroll
        for (int e = 0; e < NEXP; ++e) { p[e] = expf(lg[e] - m); s += p[e]; }
        float inv = 1.0f / s;
        rmaxv[t] = p[am] * inv;
        lam[g] = am;
        lrank[g] = atomicAdd(&lcnt[am], 1);             // LDS atomic
        #pragma unroll
        for (int e = 0; e < NEXP; ++e) atomicAdd(&sprob[e], p[e] * inv);  // LDS atomic
    }
    __syncthreads();
    if (tid < NEXP) {
        lbase[tid] = atomicAdd(&ec_p[tid*16], lcnt[tid]);   // padded: 1 line/expert
        atomicAdd(&rprob_p[tid*16], sprob[tid]);            // padded: 1 line/expert
    }
    __syncthreads();
    if (j == 0)
        elist[lam[g]*TTOT + lbase[lam[g]] + lrank[g]] = t;
}

// ---------------- pack expert weights (merged): fp32 -> bf16 B-frag --------------
__global__ void pack_experts(const float* __restrict__ w1l, const float* __restrict__ w2l,
                             unsigned short* __restrict__ w1p, unsigned short* __restrict__ w2p) {
    int tid = blockIdx.x*256 + threadIdx.x;   // 327680 per matrix set
    unsigned short o[8];
    if (blockIdx.y == 0) {
        int l = tid & 63, kk = (tid >> 6) & 7, nt = (tid >> 9) & 63, e = tid >> 15;
        const float* src = w1l + (size_t)e*262144 + (size_t)(kk*32 + (l>>4)*8)*DFFN + nt*16 + (l&15);
        #pragma unroll
        for (int j = 0; j < 8; ++j) o[j] = f2bf(src[(size_t)j*DFFN]);
        *(ulonglong2*)(w1p + (size_t)tid*8) = *(ulonglong2*)o;
    } else {
        int l = tid & 63, kk = (tid >> 6) & 31, nt = (tid >> 11) & 15, e = tid >> 15;
        const float* src = w2l + (size_t)e*262144 + (size_t)(kk*32 + (l>>4)*8)*DN + nt*16 + (l&15);
        #pragma unroll
        for (int j = 0; j < 8; ++j) o[j] = f2bf(src[(size_t)j*DN]);
        *(ulonglong2*)(w2p + (size_t)tid*8) = *(ulonglong2*)o;
    }
}

// ---------------- MoE: TM=16, 2D grid, register epilogue (42 KB LDS) -------------
#define TM 16
__global__ __launch_bounds__(256)
void moe_kernel(float* __restrict__ z, const int* __restrict__ elist,
                const int* __restrict__ ec_p, const float* __restrict__ rmaxv,
                const unsigned short* __restrict__ w1p, const float* __restrict__ b1,
                const unsigned short* __restrict__ w2p, const float* __restrict__ b2,
                const float* __restrict__ g, const float* __restrict__ bb) {
    int e = blockIdx.y;
    int cnt = ec_p[e*16];
    int base = blockIdx.x * TM;
    if (base >= cnt) return;
    int n = min(TM, cnt - base);

    __shared__ __align__(16) unsigned short ts[16*264];
    __shared__ __align__(16) unsigned short hbuf[16*1032];
    __shared__ float wsum[4][16], wsq[4][16];
    __shared__ int toks[16];
    __shared__ float rm[16];

    int tid = threadIdx.x;
    int w = tid >> 6, l = tid & 63, c = l & 15, gq = l >> 4;
    if (tid < 16) {
        int tt = (tid < n) ? elist[e*TTOT + base + tid] : 0;
        toks[tid] = tt;
        rm[tid] = rmaxv[tt];
    }
    __syncthreads();
    #pragma unroll
    for (int m = 0; m < 16; ++m)
        ts[m*264 + tid] = f2bf(z[(size_t)toks[m]*DN + tid]);
    __syncthreads();

    const bf16x8* w1v = (const bf16x8*)w1p;
    const float* b1e = b1 + e*DFFN;
    f32x4 acc[16];
    #pragma unroll
    for (int i = 0; i < 16; ++i) acc[i] = (f32x4){0.f,0.f,0.f,0.f};
    #pragma unroll
    for (int kk = 0; kk < 8; ++kk) {
        bf16x8 a = *(const bf16x8*)(ts + c*264 + kk*32 + gq*8);
        const bf16x8* wbp = w1v + (((size_t)e*64 + w*16)*8 + kk)*64 + l;
        #pragma unroll
        for (int nt2 = 0; nt2 < 16; ++nt2)
            acc[nt2] = __builtin_amdgcn_mfma_f32_16x16x32_bf16(a, wbp[nt2*512], acc[nt2], 0, 0, 0);
    }
    #pragma unroll
    for (int nt2 = 0; nt2 < 16; ++nt2) {
        int col = w*256 + nt2*16 + c;
        float bv = b1e[col];
        #pragma unroll
        for (int r = 0; r < 4; ++r) {
            int row = gq*4 + r;
            hbuf[row*1032 + col] = f2bf(fmaxf(acc[nt2][r] + bv, 0.f));
        }
    }
    __syncthreads();

    const bf16x8* w2v = (const bf16x8*)w2p;
    const float* b2e = b2 + e*DN;
    f32x4 acc2[4];
    #pragma unroll
    for (int i = 0; i < 4; ++i) acc2[i] = (f32x4){0.f,0.f,0.f,0.f};
    for (int kk = 0; kk < 32; ++kk) {
        bf16x8 a = *(const bf16x8*)(hbuf + c*1032 + kk*32 + gq*8);
        const bf16x8* wbp = w2v + (((size_t)e*16 + w*4)*32 + kk)*64 + l;
        #pragma unroll
        for (int nt2 = 0; nt2 < 4; ++nt2)
            acc2[nt2] = __builtin_amdgcn_mfma_f32_16x16x32_bf16(a, wbp[nt2*2048], acc2[nt2], 0, 0, 0);
    }

    // ---- fused residual + LN epilogue (register vals, 512 B cross-wave reduce)
    float vals[4][4];   // [nt2][r]
    float sm[4], sq2[4];
    #pragma unroll
    for (int r = 0; r < 4; ++r) { sm[r] = 0.f; sq2[r] = 0.f; }
    #pragma unroll
    for (int nt2 = 0; nt2 < 4; ++nt2) {
        int colg = w*64 + nt2*16 + c;
        float bv = b2e[colg];
        #pragma unroll
        for (int r = 0; r < 4; ++r) {
            int row = gq*4 + r;
            float v = (acc2[nt2][r] + bv) * rm[row] + z[(size_t)toks[row]*DN + colg];
            vals[nt2][r] = v;
            sm[r] += v; sq2[r] += v*v;
        }
    }
    #pragma unroll
    for (int r = 0; r < 4; ++r) {
        #pragma unroll
        for (int off = 1; off <= 8; off <<= 1) {
            sm[r] += __shfl_xor(sm[r], off, 64);
            sq2[r] += __shfl_xor(sq2[r], off, 64);
        }
    }
    if (c == 0) {
        #pragma unroll
        for (int r = 0; r < 4; ++r) {
            wsum[w][gq*4 + r] = sm[r];
            wsq[w][gq*4 + r] = sq2[r];
        }
    }
    __syncthreads();
    #pragma unroll
    for (int r = 0; r < 4; ++r) {
        int row = gq*4 + r;
        float S = wsum[0][row] + wsum[1][row] + wsum[2][row] + wsum[3][row];
        float Q = wsq[0][row] + wsq[1][row] + wsq[2][row] + wsq[3][row];
        float mu = S * (1.0f/DN);
        float var = Q * (1.0f/DN) - mu*mu;
        float rs = rsqrtf(var + 1e-5f);
        if (row < n) {
            int t = toks[row];
            #pragma unroll
            for (int nt2 = 0; nt2 < 4; ++nt2) {
                int colg = w*64 + nt2*16 + c;
                z[(size_t)t*DN + colg] = (vals[nt2][r] - mu)*rs*g[colg] + bb[colg];
            }
        }
    }
}

// ---------------- pack deconv taps -> bf16 B-frag ----------------
__global__ void pack_deconv_mfma(const float* __restrict__ w, unsigned short* __restrict__ wdp) {
    int tid = blockIdx.x*256 + threadIdx.x;   // 32768
    int l = tid & 63, kk = (tid >> 6) & 7, nt = (tid >> 9) & 15, tap = tid >> 13;
    int dout = nt*16 + (l&15);
    int din0 = kk*32 + (l>>4)*8;
    unsigned short o[8];
    #pragma unroll
    for (int j = 0; j < 8; ++j)
        o[j] = f2bf(w[((size_t)(din0 + j)*DN + dout)*4 + tap]);
    *(ulonglong2*)(wdp + (size_t)tid*8) = *(ulonglong2*)o;
}

__global__ void pack_lin1(const float* __restrict__ w, unsigned short* __restrict__ wl1) {
    int tid = blockIdx.x*256 + threadIdx.x;   // 4096
    int l = tid & 63, kk = (tid >> 6) & 7, nt = tid >> 9;
    const float* src = w + (size_t)(nt*16 + (l&15))*DN + kk*32 + (l>>4)*8;
    unsigned short o[8];
    #pragma unroll
    for (int j = 0; j < 8; ++j) o[j] = f2bf(src[j]);
    *(ulonglong2*)(wl1 + (size_t)tid*8) = *(ulonglong2*)o;
}

// ---------------- deconv as MFMA GEMM ----------------
__global__ __launch_bounds__(256)
void deconv_mfma(const float* __restrict__ z, const unsigned short* __restrict__ wdp,
                 const float* __restrict__ db, float* __restrict__ u) {
    int blk = blockIdx.x;
    int b = blk >> 4, lt = blk & 15;
    int l0 = lt * 32;
    __shared__ __align__(16) unsigned short zs[34*264];
    int tid = threadIdx.x;
    #pragma unroll
    for (int i = 0; i < 9; ++i) {
        int f4 = i*256 + tid;
        if (f4 < 34*64) {
            int row = f4 >> 6, c4 = f4 & 63;
            int l = l0 - 1 + row;
            float4 a = (l >= 0 && l < LATN)
                ? *(const float4*)&z[((size_t)b*LATN + l)*DN + c4*4]
                : make_float4(0.f, 0.f, 0.f, 0.f);
            ushort4 o = { f2bf(a.x), f2bf(a.y), f2bf(a.z), f2bf(a.w) };
            *(ushort4*)&zs[row*264 + c4*4] = o;
        }
    }
    __syncthreads();
    int w = tid >> 6, l = tid & 63;
    f32x4 acce[2][4], acco[2][4];
    #pragma unroll
    for (int m = 0; m < 2; ++m)
        #pragma unroll
        for (int n = 0; n < 4; ++n) {
            acce[m][n] = (f32x4){0.f,0.f,0.f,0.f};
            acco[m][n] = (f32x4){0.f,0.f,0.f,0.f};
        }
    const bf16x8* wdv = (const bf16x8*)wdp;
    #pragma unroll
    for (int kk = 0; kk < 8; ++kk) {
        bf16x8 a0[2], a1[2], a2[2];
        #pragma unroll
        for (int m = 0; m < 2; ++m) {
            int rb = (m*16 + (l&15))*264 + kk*32 + (l>>4)*8;
            a0[m] = *(const bf16x8*)&zs[rb];
            a1[m] = *(const bf16x8*)&zs[rb + 264];
            a2[m] = *(const bf16x8*)&zs[rb + 528];
        }
        #pragma unroll
        for (int n = 0; n < 4; ++n) {
            int nt = w*4 + n;
            bf16x8 bt0 = wdv[((0*16 + nt)*8 + kk)*64 + l];
            bf16x8 bt1 = wdv[((1*16 + nt)*8 + kk)*64 + l];
            bf16x8 bt2 = wdv[((2*16 + nt)*8 + kk)*64 + l];
            bf16x8 bt3 = wdv[((3*16 + nt)*8 + kk)*64 + l];
            #pragma unroll
            for (int m = 0; m < 2; ++m) {
                acco[m][n] = __builtin_amdgcn_mfma_f32_16x16x32_bf16(a2[m], bt0, acco[m][n], 0, 0, 0);
                acce[m][n] = __builtin_amdgcn_mfma_f32_16x16x32_bf16(a1[m], bt1, acce[m][n], 0, 0, 0);
                acco[m][n] = __builtin_amdgcn_mfma_f32_16x16x32_bf16(a1[m], bt2, acco[m][n], 0, 0, 0);
                acce[m][n] = __builtin_amdgcn_mfma_f32_16x16x32_bf16(a0[m], bt3, acce[m][n], 0, 0, 0);
            }
        }
    }
    #pragma unroll
    for (int n = 0; n < 4; ++n) {
        int col = (w*4 + n)*16 + (l&15);
        float bv = db[col];
        #pragma unroll
        for (int m = 0; m < 2; ++m) {
            #pragma unroll
            for (int r = 0; r < 4; ++r) {
                int rt = m*16 + (l>>4)*4 + r;
                int wpos = 2*(l0 + rt);
                u[((size_t)b*1024 + wpos)*DN + col]     = acce[m][n][r] + bv;
                u[((size_t)b*1024 + wpos + 1)*DN + col] = acco[m][n][r] + bv;
            }
        }
    }
}

// ---------------- head: MFMA lin1 + tanh + lin2 fused ----------------
__global__ __launch_bounds__(256)
void head_mfma(const float* __restrict__ u, const unsigned short* __restrict__ wl1,
               const float* __restrict__ b1, const float* __restrict__ w2,
               const float* __restrict__ b2, float* __restrict__ out) {
    int r0 = blockIdx.x * 64;
    __shared__ __align__(16) unsigned short us[64*264];
    __shared__ float part[4][64];
    int tid = threadIdx.x;
    #pragma unroll
    for (int i = 0; i < 16; ++i) {
        int f4 = i*256 + tid;
        int row = f4 >> 6, c4 = f4 & 63;
        float4 a = *(const float4*)&u[(size_t)(r0 + row)*DN + c4*4];
        ushort4 o = { f2bf(a.x), f2bf(a.y), f2bf(a.z), f2bf(a.w) };
        *(ushort4*)&us[row*264 + c4*4] = o;
    }
    __syncthreads();
    int w = tid >> 6, l = tid & 63;
    f32x4 acc[4][2];
    #pragma unroll
    for (int m = 0; m < 4; ++m) { acc[m][0] = (f32x4){0.f,0.f,0.f,0.f}; acc[m][1] = (f32x4){0.f,0.f,0.f,0.f}; }
    const bf16x8* wv1 = (const bf16x8*)wl1;
    #pragma unroll
    for (int kk = 0; kk < 8; ++kk) {
        bf16x8 af[4];
        #pragma unroll
        for (int m = 0; m < 4; ++m)
            af[m] = *(const bf16x8*)&us[(m*16 + (l&15))*264 + kk*32 + (l>>4)*8];
        #pragma unroll
        for (int n = 0; n < 2; ++n) {
            bf16x8 bf = wv1[((w*2 + n)*8 + kk)*64 + l];
            #pragma unroll
            for (int m = 0; m < 4; ++m)
                acc[m][n] = __builtin_amdgcn_mfma_f32_16x16x32_bf16(af[m], bf, acc[m][n], 0, 0, 0);
        }
    }
    float pm[4][4];
    #pragma unroll
    for (int m = 0; m < 4; ++m)
        #pragma unroll
        for (int r = 0; r < 4; ++r) pm[m][r] = 0.f;
    #pragma unroll
    for (int n = 0; n < 2; ++n) {
        int col = (w*2 + n)*16 + (l&15);
        float bb1 = b1[col], ww2 = w2[col];
        #pragma unroll
        for (int m = 0; m < 4; ++m)
            #pragma unroll
            for (int r = 0; r < 4; ++r)
                pm[m][r] += tanhf(acc[m][n][r] + bb1) * ww2;
    }
    #pragma unroll
    for (int off = 1; off <= 8; off <<= 1)
        #pragma unroll
        for (int m = 0; m < 4; ++m)
            #pragma unroll
            for (int r = 0; r < 4; ++r)
                pm[m][r] += __shfl_xor(pm[m][r], off, 64);
    if ((l & 15) == 0) {
        #pragma unroll
        for (int m = 0; m < 4; ++m)
            #pragma unroll
            for (int r = 0; r < 4; ++r)
                part[w][m*16 + (l>>4)*4 + r] = pm[m][r];
    }
    __syncthreads();
    if (tid < 64)
        out[r0 + tid] = part[0][tid] + part[1][tid] + part[2][tid] + part[3][tid] + b2[0];
}

// ---------------- loss ----------------
__global__ void loss_kernel(const int* __restrict__ ec_p, const float* __restrict__ rprob_p,
                            float* __restrict__ out) {
    if (threadIdx.x == 0) {
        float s = 0;
        for (int l = 0; l < 2; ++l)
            for (int e = 0; e < NEXP; ++e)
                s += (float)ec_p[l*160 + e*16] * rprob_p[l*160 + e*16];
        out[8192] = 10.0f * s / (4096.0f * 4096.0f);
    }
}

extern "C" void kernel_launch(void* const* d_in, const int* in_sizes, int n_in,
                              void* d_out, int out_size, void* d_ws, size_t ws_size,
                              hipStream_t stream) {
    const float* x        = (const float*)d_in[0];
    const float* conv_w   = (const float*)d_in[1];
    const float* conv_b   = (const float*)d_in[2];
    const float* pe       = (const float*)d_in[3];
    const float* ln0_g    = (const float*)d_in[4];
    const float* ln0_b    = (const float*)d_in[5];
    const float* wq       = (const float*)d_in[6];
    const float* bq       = (const float*)d_in[7];
    const float* wk       = (const float*)d_in[8];
    const float* bk       = (const float*)d_in[9];
    const float* wv       = (const float*)d_in[10];
    const float* bv       = (const float*)d_in[11];
    const float* wo       = (const float*)d_in[12];
    const float* bo       = (const float*)d_in[13];
    const float* ln1_g    = (const float*)d_in[14];
    const float* ln1_b    = (const float*)d_in[15];
    const float* ln2_g    = (const float*)d_in[16];
    const float* ln2_b    = (const float*)d_in[17];
    const float* router_w = (const float*)d_in[18];
    const float* router_b = (const float*)d_in[19];
    const float* e_w1     = (const float*)d_in[20];
    const float* e_b1     = (const float*)d_in[21];
    const float* e_w2     = (const float*)d_in[22];
    const float* e_b2     = (const float*)d_in[23];
    const float* deconv_w = (const float*)d_in[24];
    const float* deconv_b = (const float*)d_in[25];
    const float* lin1_w   = (const float*)d_in[26];
    const float* lin1_b   = (const float*)d_in[27];
    const float* lin2_w   = (const float*)d_in[28];
    const float* lin2_b   = (const float*)d_in[29];

    float* ws = (float*)d_ws;
    const size_t M = 1048576;
    float* z    = ws;
    unsigned short* qb  = (unsigned short*)(ws + 1*M);   // bf16 Q (pre-scaled)
    unsigned short* kb  = (unsigned short*)(ws + 2*M);   // bf16 K
    unsigned short* vtb = (unsigned short*)(ws + 3*M);   // bf16 V^T [bh][d][512]
    float* a    = ws + 4*M;
    float* rmax = ws + 6*M;
    float* rprob_p = rmax + 4096;             // 320 floats (16-stride padded)
    int* ec_p   = (int*)(rprob_p + 320);      // 320 ints (16-stride padded)
    int* elist  = ec_p + 320;                 // 2*10*4096
    unsigned short* wproj = (unsigned short*)(ws + 6*M + 98304);  // 8 x 65536 bf16 (1 MB)
    unsigned short* w1p = (unsigned short*)(ws + 1*M);  // per-layer packed over qb+kb (dead)
    unsigned short* w2p = (unsigned short*)(ws + 3*M);  // per-layer packed over vtb+a (dead)
    float* u    = ws + 1*M;                              // after layers
    unsigned short* wdp = (unsigned short*)(ws + 3*M);
    unsigned short* wl1 = (unsigned short*)(ws + 3*M + 131072 + 64);
    float* out  = (float*)d_out;

    zero_kernel<<<1, 512, 0, stream>>>(rprob_p, ec_p);
    {
        dim3 pg(32, 8);
        pack_proj<<<pg, 256, 0, stream>>>(wq, wk, wv, wo, wproj);
    }
    tokenizer_kernel<<<1024, 256, 0, stream>>>(x, conv_w, conv_b, pe, ln0_g, ln0_b, z);

    for (int l = 0; l < 2; ++l) {
        const unsigned short* wpl = wproj + (size_t)l*4*65536;
        dim3 qkvg(64, 3);
        proj_qkv<<<qkvg, 256, 0, stream>>>(z, wpl, bq + l*256, bk + l*256, bv + l*256,
                                           qb, kb, vtb);
        attn_mfma<<<256, 256, 0, stream>>>(qb, kb, vtb, a);
        proj_o_ln<<<64, 256, 0, stream>>>(a, wpl + 3*65536, bo + l*256, z,
                                          ln1_g + l*256, ln1_b + l*256);
        router_kernel<<<TTOT/RTOK, 512, 0, stream>>>(z, router_w + l*2560, router_b + l*10,
                                                     rmax, rprob_p + l*160, ec_p + l*160,
                                                     elist + l*10*TTOT);
        {
            dim3 pkg(1280, 2);
            pack_experts<<<pkg, 256, 0, stream>>>(e_w1 + (size_t)l*2621440,
                                                  e_w2 + (size_t)l*2621440, w1p, w2p);
        }
        dim3 mg(TTOT/TM, NEXP);
        moe_kernel<<<mg, 256, 0, stream>>>(z, elist + l*10*TTOT, ec_p + l*160, rmax,
                                           w1p, e_b1 + l*10240,
                                           w2p, e_b2 + l*2560,
                                           ln2_g + l*256, ln2_b + l*256);
    }

    pack_deconv_mfma<<<128, 256, 0, stream>>>(deconv_w, wdp);
    pack_lin1<<<16, 256, 0, stream>>>(lin1_w, wl1);
    deconv_mfma<<<128, 256, 0, stream>>>(z, wdp, deconv_b, u);
    head_mfma<<<128, 256, 0, stream>>>(u, wl1, lin1_b, lin2_w, lin2_b, out);
    loss_kernel<<<1, 64, 0, stream>>>(ec_p, rprob_p, out);
}

// Round 14
// 260.191 us; speedup vs baseline: 1.3883x; 1.3883x over previous
//
#include <hip/hip_runtime.h>
#include <math.h>

#define LATN 512
#define DN 256
#define DKN 128
#define TTOT 4096   // B*LAT
#define NEXP 10
#define DFFN 1024

using bf16x8 = __attribute__((ext_vector_type(8))) short;
using f32x4  = __attribute__((ext_vector_type(4))) float;

__device__ __forceinline__ float dot4(float4 a, float4 b) {
    return a.x*b.x + a.y*b.y + a.z*b.z + a.w*b.w;
}

__device__ __forceinline__ unsigned short f2bf(float f) {
    union { float f; unsigned int u; } v; v.f = f;
    unsigned int u = v.u + 0x7FFFu + ((v.u >> 16) & 1u);
    return (unsigned short)(u >> 16);
}

__device__ __forceinline__ float wave_sum(float x) {
    #pragma unroll
    for (int off = 32; off; off >>= 1) x += __shfl_xor(x, off, 64);
    return x;
}

// ---------------- zero init (padded counters) ----------------
__global__ void zero_kernel(float* rprob_p, int* ec_p) {
    int i = threadIdx.x;
    if (i < 320) { rprob_p[i] = 0.f; ec_p[i] = 0; }
}

// ---------------- tokenizer: wave-per-token, shfl-only LN ----------------
__global__ __launch_bounds__(256)
void tokenizer_kernel(const float* __restrict__ x, const float* __restrict__ cw,
                      const float* __restrict__ cb, const float* __restrict__ pe,
                      const float* __restrict__ g, const float* __restrict__ bb,
                      float* __restrict__ z) {
    int tid = threadIdx.x;
    int w = tid >> 6, l = tid & 63;
    int t = blockIdx.x*4 + w;
    int lt = t & (LATN - 1);
    int b = t >> 9;
    const float* xb = x + (size_t)b * 1024;
    int p0 = 2 * lt;
    float xv[6];
    #pragma unroll
    for (int i = 0; i < 6; ++i) {
        int p = min(max(p0 - 2 + i, 0), 1023);
        xv[i] = xb[p];
    }
    float v[4]; float s = 0.f, q = 0.f;
    #pragma unroll
    for (int c = 0; c < 4; ++c) {
        int d = l + 64*c;
        float w0 = cw[d*5+0], w1 = cw[d*5+1], w2 = cw[d*5+2], w3 = cw[d*5+3], w4 = cw[d*5+4];
        float bv = cb[d];
        float h0 = bv + w0*xv[0] + w1*xv[1] + w2*xv[2] + w3*xv[3] + w4*xv[4];
        float h1 = bv + w0*xv[1] + w1*xv[2] + w2*xv[3] + w3*xv[4] + w4*xv[5];
        float pool = sqrtf(h0*h0 + h1*h1);
        float val = pool + pe[lt*DN + d];
        v[c] = val; s += val; q += val*val;
    }
    s = wave_sum(s); q = wave_sum(q);
    float mu = s * (1.0f/DN);
    float var = q * (1.0f/DN) - mu*mu;
    float rs = rsqrtf(var + 1e-5f);
    #pragma unroll
    for (int c = 0; c < 4; ++c) {
        int d = l + 64*c;
        z[(size_t)t*DN + d] = (v[c] - mu)*rs*g[d] + bb[d];
    }
}

// ---------------- pack projection weights: fp32 [out,in] -> bf16 B-frag ----------
__global__ void pack_proj(const float* __restrict__ wq, const float* __restrict__ wk,
                          const float* __restrict__ wv, const float* __restrict__ wo,
                          unsigned short* __restrict__ wp) {
    int mat = blockIdx.y;              // 0..7 : layer*4 + {q,k,v,o}
    int l0 = mat >> 2, which = mat & 3;
    const float* base = (which == 0) ? wq : (which == 1) ? wk : (which == 2) ? wv : wo;
    const float* W = base + l0*65536;
    int tid = blockIdx.x*256 + threadIdx.x;   // 0..8191
    int l = tid & 63, kk = (tid >> 6) & 7, nt = tid >> 9;
    const float* src = W + (size_t)(nt*16 + (l&15))*DN + kk*32 + (l>>4)*8;
    unsigned short o[8];
    #pragma unroll
    for (int j = 0; j < 8; ++j) o[j] = f2bf(src[j]);
    *(ulonglong2*)(wp + (size_t)mat*65536 + (size_t)tid*8) = *(ulonglong2*)o;
}

// ---------------- MFMA projection GEMM body. OM: 1=bf16 out, 2=bf16 vT ----------
template<int OM>
__device__ __forceinline__ void proj_body(const float* __restrict__ A,
                                          const unsigned short* __restrict__ wpm,
                                          const float* __restrict__ bias,
                                          void* __restrict__ outp, int t0, float oscale,
                                          unsigned short* ts) {
    int tid = threadIdx.x;
    #pragma unroll
    for (int i = 0; i < 16; ++i) {
        int f4 = i*256 + tid;
        int row = f4 >> 6, c4 = f4 & 63;
        float4 a = *(const float4*)&A[(size_t)(t0+row)*DN + c4*4];
        ushort4 o = { f2bf(a.x), f2bf(a.y), f2bf(a.z), f2bf(a.w) };
        *(ushort4*)&ts[row*264 + c4*4] = o;
    }
    __syncthreads();
    int w = tid >> 6, l = tid & 63;
    f32x4 acc[4][4];
    #pragma unroll
    for (int m = 0; m < 4; ++m)
        #pragma unroll
        for (int n = 0; n < 4; ++n) acc[m][n] = (f32x4){0.f,0.f,0.f,0.f};
    const bf16x8* wv = (const bf16x8*)wpm;
    #pragma unroll
    for (int kk = 0; kk < 8; ++kk) {
        bf16x8 af[4];
        #pragma unroll
        for (int m = 0; m < 4; ++m)
            af[m] = *(const bf16x8*)&ts[(m*16 + (l&15))*264 + kk*32 + (l>>4)*8];
        #pragma unroll
        for (int n = 0; n < 4; ++n) {
            bf16x8 bf = wv[((w*4 + n)*8 + kk)*64 + l];
            #pragma unroll
            for (int m = 0; m < 4; ++m)
                acc[m][n] = __builtin_amdgcn_mfma_f32_16x16x32_bf16(af[m], bf, acc[m][n], 0, 0, 0);
        }
    }
    #pragma unroll
    for (int n = 0; n < 4; ++n) {
        int col = w*64 + n*16 + (l&15);
        float bv2 = bias[col];
        #pragma unroll
        for (int m = 0; m < 4; ++m) {
            #pragma unroll
            for (int r = 0; r < 4; ++r) {
                int row = t0 + m*16 + (l>>4)*4 + r;
                float val = acc[m][n][r] + bv2;
                if (OM == 1)
                    ((unsigned short*)outp)[(size_t)row*DN + col] = f2bf(val * oscale);
                else
                    ((unsigned short*)outp)[(((size_t)(row>>9)*2 + (col>>7))*128 + (col&127))*512 + (row&511)] = f2bf(val);
            }
        }
    }
}

__global__ __launch_bounds__(256)
void proj_qkv(const float* __restrict__ z, const unsigned short* __restrict__ wp,
              const float* __restrict__ bq, const float* __restrict__ bk,
              const float* __restrict__ bv,
              unsigned short* __restrict__ qb, unsigned short* __restrict__ kb,
              unsigned short* __restrict__ vtb) {
    __shared__ unsigned short ts[64*264];
    int mat = blockIdx.y;
    if (mat == 0)      proj_body<1>(z, wp,          bq, qb,  blockIdx.x*64, 0.08838834764831844f, ts);
    else if (mat == 1) proj_body<1>(z, wp + 65536,  bk, kb,  blockIdx.x*64, 1.0f, ts);
    else               proj_body<2>(z, wp + 131072, bv, vtb, blockIdx.x*64, 1.0f, ts);
}

// ---------------- out-proj + residual + LN fused (writes z in place) ------------
__global__ __launch_bounds__(256)
void proj_o_ln(const float* __restrict__ A, const unsigned short* __restrict__ wpm,
               const float* __restrict__ bias, float* __restrict__ z,
               const float* __restrict__ lng, const float* __restrict__ lnb) {
    __shared__ unsigned short ts[64*264];
    __shared__ float wsum[4][64], wsq[4][64];
    int t0 = blockIdx.x * 64;
    int tid = threadIdx.x;
    #pragma unroll
    for (int i = 0; i < 16; ++i) {
        int f4 = i*256 + tid;
        int row = f4 >> 6, c4 = f4 & 63;
        float4 a = *(const float4*)&A[(size_t)(t0+row)*DN + c4*4];
        ushort4 o = { f2bf(a.x), f2bf(a.y), f2bf(a.z), f2bf(a.w) };
        *(ushort4*)&ts[row*264 + c4*4] = o;
    }
    __syncthreads();
    int w = tid >> 6, l = tid & 63, c = l & 15, g = l >> 4;
    f32x4 acc[4][4];
    #pragma unroll
    for (int m = 0; m < 4; ++m)
        #pragma unroll
        for (int n = 0; n < 4; ++n) acc[m][n] = (f32x4){0.f,0.f,0.f,0.f};
    const bf16x8* wv = (const bf16x8*)wpm;
    #pragma unroll
    for (int kk = 0; kk < 8; ++kk) {
        bf16x8 af[4];
        #pragma unroll
        for (int m = 0; m < 4; ++m)
            af[m] = *(const bf16x8*)&ts[(m*16 + c)*264 + kk*32 + g*8];
        #pragma unroll
        for (int n = 0; n < 4; ++n) {
            bf16x8 bf = wv[((w*4 + n)*8 + kk)*64 + l];
            #pragma unroll
            for (int m = 0; m < 4; ++m)
                acc[m][n] = __builtin_amdgcn_mfma_f32_16x16x32_bf16(af[m], bf, acc[m][n], 0, 0, 0);
        }
    }
    float vals[4][4][4];
    float sm[4][4], sq[4][4];
    #pragma unroll
    for (int m = 0; m < 4; ++m)
        #pragma unroll
        for (int r = 0; r < 4; ++r) { sm[m][r] = 0.f; sq[m][r] = 0.f; }
    #pragma unroll
    for (int n = 0; n < 4; ++n) {
        int col = w*64 + n*16 + c;
        float bv2 = bias[col];
        #pragma unroll
        for (int m = 0; m < 4; ++m)
            #pragma unroll
            for (int r = 0; r < 4; ++r) {
                int row = t0 + m*16 + g*4 + r;
                float v = acc[m][n][r] + bv2 + z[(size_t)row*DN + col];
                vals[m][n][r] = v;
                sm[m][r] += v; sq[m][r] += v*v;
            }
    }
    #pragma unroll
    for (int m = 0; m < 4; ++m)
        #pragma unroll
        for (int r = 0; r < 4; ++r) {
            #pragma unroll
            for (int off = 1; off <= 8; off <<= 1) {
                sm[m][r] += __shfl_xor(sm[m][r], off, 64);
                sq[m][r] += __shfl_xor(sq[m][r], off, 64);
            }
        }
    if (c == 0) {
        #pragma unroll
        for (int m = 0; m < 4; ++m)
            #pragma unroll
            for (int r = 0; r < 4; ++r) {
                wsum[w][m*16 + g*4 + r] = sm[m][r];
                wsq[w][m*16 + g*4 + r] = sq[m][r];
            }
    }
    __syncthreads();
    #pragma unroll
    for (int m = 0; m < 4; ++m)
        #pragma unroll
        for (int r = 0; r < 4; ++r) {
            int rl = m*16 + g*4 + r;
            float S = wsum[0][rl] + wsum[1][rl] + wsum[2][rl] + wsum[3][rl];
            float Q = wsq[0][rl] + wsq[1][rl] + wsq[2][rl] + wsq[3][rl];
            float mu = S * (1.0f/DN);
            float var = Q * (1.0f/DN) - mu*mu;
            float rs = rsqrtf(var + 1e-5f);
            int row = t0 + rl;
            #pragma unroll
            for (int n = 0; n < 4; ++n) {
                int col = w*64 + n*16 + c;
                z[(size_t)row*DN + col] = (vals[m][n][r] - mu)*rs*lng[col] + lnb[col];
            }
        }
}

// ---------------- MFMA attention: swapped QK^T (S^T), in-reg softmax, PV via LDS-P
__global__ __launch_bounds__(256)
void attn_mfma(const unsigned short* __restrict__ qb, const unsigned short* __restrict__ kb,
               const unsigned short* __restrict__ vtb, float* __restrict__ a) {
    int blk = blockIdx.x;
    int xcd = blk & 7, idx = blk >> 3;
    int bh = xcd*2 + (idx & 1);        // 2 bh per XCD -> 1 MB L2 working set
    int qt = idx >> 1;
    int b = bh >> 1, h = bh & 1;
    int q0 = qt * 32;
    int tid = threadIdx.x;
    int w = tid >> 6, l = tid & 63;
    int c = l & 15, g = l >> 4;

    __shared__ __align__(16) unsigned short p_lds[32*512];  // [q][key] bf16, XOR-swizzled
    __shared__ float smax[4][2][16];
    __shared__ float ssum[4][2][16];

    bf16x8 qf_[2][4];
    #pragma unroll
    for (int qf = 0; qf < 2; ++qf)
        #pragma unroll
        for (int kk = 0; kk < 4; ++kk)
            qf_[qf][kk] = *(const bf16x8*)&qb[((size_t)(b*LATN + q0 + qf*16 + c))*DN + h*DKN + kk*32 + g*8];

    f32x4 st[8][2];
    #pragma unroll
    for (int f = 0; f < 8; ++f) { st[f][0] = (f32x4){0,0,0,0}; st[f][1] = (f32x4){0,0,0,0}; }
    #pragma unroll
    for (int f = 0; f < 8; ++f) {
        int kbase = w*128 + f*16;
        bf16x8 kf[4];
        #pragma unroll
        for (int kk = 0; kk < 4; ++kk)
            kf[kk] = *(const bf16x8*)&kb[((size_t)(b*LATN + kbase + c))*DN + h*DKN + kk*32 + g*8];
        #pragma unroll
        for (int kk = 0; kk < 4; ++kk) {
            st[f][0] = __builtin_amdgcn_mfma_f32_16x16x32_bf16(kf[kk], qf_[0][kk], st[f][0], 0, 0, 0);
            st[f][1] = __builtin_amdgcn_mfma_f32_16x16x32_bf16(kf[kk], qf_[1][kk], st[f][1], 0, 0, 0);
        }
    }

    float gmax[2], ginv[2];
    #pragma unroll
    for (int qf = 0; qf < 2; ++qf) {
        float m = -1e30f;
        #pragma unroll
        for (int f = 0; f < 8; ++f)
            #pragma unroll
            for (int r = 0; r < 4; ++r) m = fmaxf(m, st[f][qf][r]);
        m = fmaxf(m, __shfl_xor(m, 16, 64));
        m = fmaxf(m, __shfl_xor(m, 32, 64));
        if (l < 16) smax[w][qf][l] = m;
    }
    __syncthreads();
    #pragma unroll
    for (int qf = 0; qf < 2; ++qf)
        gmax[qf] = fmaxf(fmaxf(smax[0][qf][c], smax[1][qf][c]),
                         fmaxf(smax[2][qf][c], smax[3][qf][c]));
    #pragma unroll
    for (int qf = 0; qf < 2; ++qf) {
        float s = 0.f;
        #pragma unroll
        for (int f = 0; f < 8; ++f)
            #pragma unroll
            for (int r = 0; r < 4; ++r) {
                float e = __expf(st[f][qf][r] - gmax[qf]);
                st[f][qf][r] = e; s += e;
            }
        s += __shfl_xor(s, 16, 64);
        s += __shfl_xor(s, 32, 64);
        if (l < 16) ssum[w][qf][l] = s;
    }
    __syncthreads();
    #pragma unroll
    for (int qf = 0; qf < 2; ++qf)
        ginv[qf] = 1.0f / (ssum[0][qf][c] + ssum[1][qf][c] + ssum[2][qf][c] + ssum[3][qf][c]);

    #pragma unroll
    for (int qf = 0; qf < 2; ++qf) {
        int q_ = qf*16 + c;
        int rowb = q_ * 1024;
        int swz = (q_ & 7) << 4;
        float iv = ginv[qf];
        #pragma unroll
        for (int f = 0; f < 8; ++f) {
            unsigned int lo = (unsigned int)f2bf(st[f][qf][0]*iv) |
                              ((unsigned int)f2bf(st[f][qf][1]*iv) << 16);
            unsigned int hi = (unsigned int)f2bf(st[f][qf][2]*iv) |
                              ((unsigned int)f2bf(st[f][qf][3]*iv) << 16);
            int key0 = w*128 + f*16 + g*4;
            *(unsigned long long*)((char*)p_lds + rowb + ((key0*2) ^ swz)) =
                (unsigned long long)lo | ((unsigned long long)hi << 32);
        }
    }
    __syncthreads();

    f32x4 o[2][2];
    o[0][0] = (f32x4){0,0,0,0}; o[0][1] = (f32x4){0,0,0,0};
    o[1][0] = (f32x4){0,0,0,0}; o[1][1] = (f32x4){0,0,0,0};
    #pragma unroll
    for (int kk = 0; kk < 16; ++kk) {
        bf16x8 pb[2];
        #pragma unroll
        for (int qf = 0; qf < 2; ++qf) {
            int q_ = qf*16 + c;
            pb[qf] = *(const bf16x8*)((const char*)p_lds + q_*1024 +
                                      (((kk*32 + g*8)*2) ^ ((q_&7)<<4)));
        }
        bf16x8 va[2];
        #pragma unroll
        for (int m = 0; m < 2; ++m)
            va[m] = *(const bf16x8*)&vtb[((size_t)(bh*128 + w*32 + m*16 + c))*512 + kk*32 + g*8];
        #pragma unroll
        for (int m = 0; m < 2; ++m) {
            o[m][0] = __builtin_amdgcn_mfma_f32_16x16x32_bf16(va[m], pb[0], o[m][0], 0, 0, 0);
            o[m][1] = __builtin_amdgcn_mfma_f32_16x16x32_bf16(va[m], pb[1], o[m][1], 0, 0, 0);
        }
    }
    #pragma unroll
    for (int m = 0; m < 2; ++m)
        #pragma unroll
        for (int qf = 0; qf < 2; ++qf)
            #pragma unroll
            for (int r = 0; r < 4; ++r) {
                int d = w*32 + m*16 + g*4 + r;
                a[((size_t)(b*LATN + q0 + qf*16 + c))*DN + h*DKN + d] = o[m][qf][r];
            }
}

// ---------------- router: 32 tokens/block, block-aggregated padded atomics ----
#define RTOK 32
__global__ __launch_bounds__(512)
void router_kernel(const float* __restrict__ z, const float* __restrict__ rw,
                   const float* __restrict__ rb, float* __restrict__ rmaxv,
                   float* __restrict__ rprob_p, int* __restrict__ ec_p,
                   int* __restrict__ elist) {
    __shared__ float rws[NEXP*DN];
    __shared__ float sprob[NEXP];
    __shared__ int lcnt[NEXP], lbase[NEXP];
    __shared__ int lrank[RTOK];
    __shared__ int lam[RTOK];
    int tid = threadIdx.x;
    for (int i = tid; i < NEXP*DN; i += 512) rws[i] = rw[i];
    if (tid < NEXP) { sprob[tid] = 0.f; lcnt[tid] = 0; }
    __syncthreads();
    int g = tid >> 4, j = tid & 15;
    int t = blockIdx.x * RTOK + g;
    const float4* z4 = (const float4*)&z[(size_t)t*DN + j*16];
    const float4* rws4 = (const float4*)rws;
    float acc[NEXP];
    #pragma unroll
    for (int e = 0; e < NEXP; ++e) acc[e] = 0.f;
    int r0 = (j >> 1) & 3;
    #pragma unroll
    for (int kq = 0; kq < 4; ++kq) {
        int k4 = (kq + r0) & 3;
        float4 zv = z4[k4];
        #pragma unroll
        for (int e = 0; e < NEXP; ++e)
            acc[e] += dot4(zv, rws4[e*64 + j*4 + k4]);
    }
    #pragma unroll
    for (int e = 0; e < NEXP; ++e) {
        acc[e] += __shfl_xor(acc[e], 1, 64);
        acc[e] += __shfl_xor(acc[e], 2, 64);
        acc[e] += __shfl_xor(acc[e], 4, 64);
        acc[e] += __shfl_xor(acc[e], 8, 64);
    }
    if (j == 0) {
        float lg[NEXP];
        float m = acc[0] + rb[0]; int am = 0;
        lg[0] = m;
        #pragma unroll
        for (int e = 1; e < NEXP; ++e) {
            lg[e] = acc[e] + rb[e];
            if (lg[e] > m) { m = lg[e]; am = e; }
        }
        float p[NEXP], s = 0.f;
        #pragma unroll
        for (int e = 0; e < NEXP; ++e) { p[e] = expf(lg[e] - m); s += p[e]; }
        float inv = 1.0f / s;
        rmaxv[t] = p[am] * inv;
        lam[g] = am;
        lrank[g] = atomicAdd(&lcnt[am], 1);             // LDS atomic
        #pragma unroll
        for (int e = 0; e < NEXP; ++e) atomicAdd(&sprob[e], p[e] * inv);  // LDS atomic
    }
    __syncthreads();
    if (tid < NEXP) {
        lbase[tid] = atomicAdd(&ec_p[tid*16], lcnt[tid]);   // padded: 1 line/expert
        atomicAdd(&rprob_p[tid*16], sprob[tid]);            // padded: 1 line/expert
    }
    __syncthreads();
    if (j == 0)
        elist[lam[g]*TTOT + lbase[lam[g]] + lrank[g]] = t;
}

// ---------------- pack expert weights (merged): fp32 -> bf16 B-frag --------------
__global__ void pack_experts(const float* __restrict__ w1l, const float* __restrict__ w2l,
                             unsigned short* __restrict__ w1p, unsigned short* __restrict__ w2p) {
    int tid = blockIdx.x*256 + threadIdx.x;   // 327680 per matrix set
    unsigned short o[8];
    if (blockIdx.y == 0) {
        int l = tid & 63, kk = (tid >> 6) & 7, nt = (tid >> 9) & 63, e = tid >> 15;
        const float* src = w1l + (size_t)e*262144 + (size_t)(kk*32 + (l>>4)*8)*DFFN + nt*16 + (l&15);
        #pragma unroll
        for (int j = 0; j < 8; ++j) o[j] = f2bf(src[(size_t)j*DFFN]);
        *(ulonglong2*)(w1p + (size_t)tid*8) = *(ulonglong2*)o;
    } else {
        int l = tid & 63, kk = (tid >> 6) & 31, nt = (tid >> 11) & 15, e = tid >> 15;
        const float* src = w2l + (size_t)e*262144 + (size_t)(kk*32 + (l>>4)*8)*DN + nt*16 + (l&15);
        #pragma unroll
        for (int j = 0; j < 8; ++j) o[j] = f2bf(src[(size_t)j*DN]);
        *(ulonglong2*)(w2p + (size_t)tid*8) = *(ulonglong2*)o;
    }
}

// ---------------- MoE: TM=16, 2D grid, 8 waves/block (round-12 dataflow) ---------
#define TM 16
__global__ __launch_bounds__(512)
void moe_kernel(float* __restrict__ z, const int* __restrict__ elist,
                const int* __restrict__ ec_p, const float* __restrict__ rmaxv,
                const unsigned short* __restrict__ w1p, const float* __restrict__ b1,
                const unsigned short* __restrict__ w2p, const float* __restrict__ b2,
                const float* __restrict__ g, const float* __restrict__ bb) {
    int e = blockIdx.y;
    int cnt = ec_p[e*16];
    int base = blockIdx.x * TM;
    if (base >= cnt) return;
    int n = min(TM, cnt - base);

    __shared__ __align__(16) unsigned short ts[16*264];
    __shared__ __align__(16) unsigned short hbuf[16*1032];
    __shared__ __align__(16) float ybuf[16*260];
    __shared__ int toks[16];
    __shared__ float rm[16];

    int tid = threadIdx.x;
    int w = tid >> 6, l = tid & 63, c = l & 15, gq = l >> 4;
    if (tid < 16) {
        int tt = (tid < n) ? elist[e*TTOT + base + tid] : 0;
        toks[tid] = tt;
        rm[tid] = rmaxv[tt];
    }
    __syncthreads();
    {
        int half = tid >> 8, colx = tid & 255;
        #pragma unroll
        for (int m = 0; m < 8; ++m)
            ts[(half*8 + m)*264 + colx] = f2bf(z[(size_t)toks[half*8 + m]*DN + colx]);
    }
    __syncthreads();

    // GEMM1: wave w owns cols [w*128, w*128+128)  (8 nt-tiles)
    const bf16x8* w1v = (const bf16x8*)w1p;
    const float* b1e = b1 + e*DFFN;
    f32x4 acc[8];
    #pragma unroll
    for (int i = 0; i < 8; ++i) acc[i] = (f32x4){0.f,0.f,0.f,0.f};
    #pragma unroll
    for (int kk = 0; kk < 8; ++kk) {
        bf16x8 a = *(const bf16x8*)(ts + c*264 + kk*32 + gq*8);
        const bf16x8* wbp = w1v + (((size_t)e*64 + w*8)*8 + kk)*64 + l;
        #pragma unroll
        for (int nt2 = 0; nt2 < 8; ++nt2)
            acc[nt2] = __builtin_amdgcn_mfma_f32_16x16x32_bf16(a, wbp[nt2*512], acc[nt2], 0, 0, 0);
    }
    #pragma unroll
    for (int nt2 = 0; nt2 < 8; ++nt2) {
        int col = w*128 + nt2*16 + c;
        float bv = b1e[col];
        #pragma unroll
        for (int r = 0; r < 4; ++r) {
            int row = gq*4 + r;
            hbuf[row*1032 + col] = f2bf(fmaxf(acc[nt2][r] + bv, 0.f));
        }
    }
    __syncthreads();

    // GEMM2: wave w owns cols [w*32, w*32+32)  (2 nt2-tiles)
    const bf16x8* w2v = (const bf16x8*)w2p;
    const float* b2e = b2 + e*DN;
    f32x4 acc2[2];
    acc2[0] = (f32x4){0.f,0.f,0.f,0.f};
    acc2[1] = (f32x4){0.f,0.f,0.f,0.f};
    for (int kk = 0; kk < 32; ++kk) {
        bf16x8 a = *(const bf16x8*)(hbuf + c*1032 + kk*32 + gq*8);
        const bf16x8* wbp = w2v + (((size_t)e*16 + w*2)*32 + kk)*64 + l;
        acc2[0] = __builtin_amdgcn_mfma_f32_16x16x32_bf16(a, wbp[0], acc2[0], 0, 0, 0);
        acc2[1] = __builtin_amdgcn_mfma_f32_16x16x32_bf16(a, wbp[2048], acc2[1], 0, 0, 0);
    }
    #pragma unroll
    for (int nt2 = 0; nt2 < 2; ++nt2) {
        int col = w*32 + nt2*16 + c;
        float bv = b2e[col];
        #pragma unroll
        for (int r = 0; r < 4; ++r) {
            int row = gq*4 + r;
            ybuf[row*260 + col] = (acc2[nt2][r] + bv) * rm[row];
        }
    }
    __syncthreads();

    // residual + LN: wave w owns rows w*2..w*2+1 (round-12 verified epilogue)
    #pragma unroll
    for (int rr = 0; rr < 2; ++rr) {
        int row = w*2 + rr;
        if (row < n) {
            int t = toks[row];
            float v[4];
            #pragma unroll
            for (int cc = 0; cc < 4; ++cc)
                v[cc] = ybuf[row*260 + l + 64*cc] + z[(size_t)t*DN + l + 64*cc];
            float s = wave_sum(v[0]+v[1]+v[2]+v[3]);
            float mu = s * (1.0f/DN);
            float s2 = 0.f;
            #pragma unroll
            for (int cc = 0; cc < 4; ++cc) { v[cc] -= mu; s2 += v[cc]*v[cc]; }
            s2 = wave_sum(s2);
            float rs = rsqrtf(s2 * (1.0f/DN) + 1e-5f);
            #pragma unroll
            for (int cc = 0; cc < 4; ++cc) {
                int col = l + 64*cc;
                z[(size_t)t*DN + col] = v[cc]*rs*g[col] + bb[col];
            }
        }
    }
}

// ---------------- pack deconv taps -> bf16 B-frag ----------------
__global__ void pack_deconv_mfma(const float* __restrict__ w, unsigned short* __restrict__ wdp) {
    int tid = blockIdx.x*256 + threadIdx.x;   // 32768
    int l = tid & 63, kk = (tid >> 6) & 7, nt = (tid >> 9) & 15, tap = tid >> 13;
    int dout = nt*16 + (l&15);
    int din0 = kk*32 + (l>>4)*8;
    unsigned short o[8];
    #pragma unroll
    for (int j = 0; j < 8; ++j)
        o[j] = f2bf(w[((size_t)(din0 + j)*DN + dout)*4 + tap]);
    *(ulonglong2*)(wdp + (size_t)tid*8) = *(ulonglong2*)o;
}

__global__ void pack_lin1(const float* __restrict__ w, unsigned short* __restrict__ wl1) {
    int tid = blockIdx.x*256 + threadIdx.x;   // 4096
    int l = tid & 63, kk = (tid >> 6) & 7, nt = tid >> 9;
    const float* src = w + (size_t)(nt*16 + (l&15))*DN + kk*32 + (l>>4)*8;
    unsigned short o[8];
    #pragma unroll
    for (int j = 0; j < 8; ++j) o[j] = f2bf(src[j]);
    *(ulonglong2*)(wl1 + (size_t)tid*8) = *(ulonglong2*)o;
}

// ---------------- deconv as MFMA GEMM ----------------
__global__ __launch_bounds__(256)
void deconv_mfma(const float* __restrict__ z, const unsigned short* __restrict__ wdp,
                 const float* __restrict__ db, float* __restrict__ u) {
    int blk = blockIdx.x;
    int b = blk >> 4, lt = blk & 15;
    int l0 = lt * 32;
    __shared__ __align__(16) unsigned short zs[34*264];
    int tid = threadIdx.x;
    #pragma unroll
    for (int i = 0; i < 9; ++i) {
        int f4 = i*256 + tid;
        if (f4 < 34*64) {
            int row = f4 >> 6, c4 = f4 & 63;
            int l = l0 - 1 + row;
            float4 a = (l >= 0 && l < LATN)
                ? *(const float4*)&z[((size_t)b*LATN + l)*DN + c4*4]
                : make_float4(0.f, 0.f, 0.f, 0.f);
            ushort4 o = { f2bf(a.x), f2bf(a.y), f2bf(a.z), f2bf(a.w) };
            *(ushort4*)&zs[row*264 + c4*4] = o;
        }
    }
    __syncthreads();
    int w = tid >> 6, l = tid & 63;
    f32x4 acce[2][4], acco[2][4];
    #pragma unroll
    for (int m = 0; m < 2; ++m)
        #pragma unroll
        for (int n = 0; n < 4; ++n) {
            acce[m][n] = (f32x4){0.f,0.f,0.f,0.f};
            acco[m][n] = (f32x4){0.f,0.f,0.f,0.f};
        }
    const bf16x8* wdv = (const bf16x8*)wdp;
    #pragma unroll
    for (int kk = 0; kk < 8; ++kk) {
        bf16x8 a0[2], a1[2], a2[2];
        #pragma unroll
        for (int m = 0; m < 2; ++m) {
            int rb = (m*16 + (l&15))*264 + kk*32 + (l>>4)*8;
            a0[m] = *(const bf16x8*)&zs[rb];
            a1[m] = *(const bf16x8*)&zs[rb + 264];
            a2[m] = *(const bf16x8*)&zs[rb + 528];
        }
        #pragma unroll
        for (int n = 0; n < 4; ++n) {
            int nt = w*4 + n;
            bf16x8 bt0 = wdv[((0*16 + nt)*8 + kk)*64 + l];
            bf16x8 bt1 = wdv[((1*16 + nt)*8 + kk)*64 + l];
            bf16x8 bt2 = wdv[((2*16 + nt)*8 + kk)*64 + l];
            bf16x8 bt3 = wdv[((3*16 + nt)*8 + kk)*64 + l];
            #pragma unroll
            for (int m = 0; m < 2; ++m) {
                acco[m][n] = __builtin_amdgcn_mfma_f32_16x16x32_bf16(a2[m], bt0, acco[m][n], 0, 0, 0);
                acce[m][n] = __builtin_amdgcn_mfma_f32_16x16x32_bf16(a1[m], bt1, acce[m][n], 0, 0, 0);
                acco[m][n] = __builtin_amdgcn_mfma_f32_16x16x32_bf16(a1[m], bt2, acco[m][n], 0, 0, 0);
                acce[m][n] = __builtin_amdgcn_mfma_f32_16x16x32_bf16(a0[m], bt3, acce[m][n], 0, 0, 0);
            }
        }
    }
    #pragma unroll
    for (int n = 0; n < 4; ++n) {
        int col = (w*4 + n)*16 + (l&15);
        float bv = db[col];
        #pragma unroll
        for (int m = 0; m < 2; ++m) {
            #pragma unroll
            for (int r = 0; r < 4; ++r) {
                int rt = m*16 + (l>>4)*4 + r;
                int wpos = 2*(l0 + rt);
                u[((size_t)b*1024 + wpos)*DN + col]     = acce[m][n][r] + bv;
                u[((size_t)b*1024 + wpos + 1)*DN + col] = acco[m][n][r] + bv;
            }
        }
    }
}

// ---------------- head: MFMA lin1 + tanh + lin2 fused ----------------
__global__ __launch_bounds__(256)
void head_mfma(const float* __restrict__ u, const unsigned short* __restrict__ wl1,
               const float* __restrict__ b1, const float* __restrict__ w2,
               const float* __restrict__ b2, float* __restrict__ out) {
    int r0 = blockIdx.x * 64;
    __shared__ __align__(16) unsigned short us[64*264];
    __shared__ float part[4][64];
    int tid = threadIdx.x;
    #pragma unroll
    for (int i = 0; i < 16; ++i) {
        int f4 = i*256 + tid;
        int row = f4 >> 6, c4 = f4 & 63;
        float4 a = *(const float4*)&u[(size_t)(r0 + row)*DN + c4*4];
        ushort4 o = { f2bf(a.x), f2bf(a.y), f2bf(a.z), f2bf(a.w) };
        *(ushort4*)&us[row*264 + c4*4] = o;
    }
    __syncthreads();
    int w = tid >> 6, l = tid & 63;
    f32x4 acc[4][2];
    #pragma unroll
    for (int m = 0; m < 4; ++m) { acc[m][0] = (f32x4){0.f,0.f,0.f,0.f}; acc[m][1] = (f32x4){0.f,0.f,0.f,0.f}; }
    const bf16x8* wv1 = (const bf16x8*)wl1;
    #pragma unroll
    for (int kk = 0; kk < 8; ++kk) {
        bf16x8 af[4];
        #pragma unroll
        for (int m = 0; m < 4; ++m)
            af[m] = *(const bf16x8*)&us[(m*16 + (l&15))*264 + kk*32 + (l>>4)*8];
        #pragma unroll
        for (int n = 0; n < 2; ++n) {
            bf16x8 bf = wv1[((w*2 + n)*8 + kk)*64 + l];
            #pragma unroll
            for (int m = 0; m < 4; ++m)
                acc[m][n] = __builtin_amdgcn_mfma_f32_16x16x32_bf16(af[m], bf, acc[m][n], 0, 0, 0);
        }
    }
    float pm[4][4];
    #pragma unroll
    for (int m = 0; m < 4; ++m)
        #pragma unroll
        for (int r = 0; r < 4; ++r) pm[m][r] = 0.f;
    #pragma unroll
    for (int n = 0; n < 2; ++n) {
        int col = (w*2 + n)*16 + (l&15);
        float bb1 = b1[col], ww2 = w2[col];
        #pragma unroll
        for (int m = 0; m < 4; ++m)
            #pragma unroll
            for (int r = 0; r < 4; ++r)
                pm[m][r] += tanhf(acc[m][n][r] + bb1) * ww2;
    }
    #pragma unroll
    for (int off = 1; off <= 8; off <<= 1)
        #pragma unroll
        for (int m = 0; m < 4; ++m)
            #pragma unroll
            for (int r = 0; r < 4; ++r)
                pm[m][r] += __shfl_xor(pm[m][r], off, 64);
    if ((l & 15) == 0) {
        #pragma unroll
        for (int m = 0; m < 4; ++m)
            #pragma unroll
            for (int r = 0; r < 4; ++r)
                part[w][m*16 + (l>>4)*4 + r] = pm[m][r];
    }
    __syncthreads();
    if (tid < 64)
        out[r0 + tid] = part[0][tid] + part[1][tid] + part[2][tid] + part[3][tid] + b2[0];
}

// ---------------- loss ----------------
__global__ void loss_kernel(const int* __restrict__ ec_p, const float* __restrict__ rprob_p,
                            float* __restrict__ out) {
    if (threadIdx.x == 0) {
        float s = 0;
        for (int l = 0; l < 2; ++l)
            for (int e = 0; e < NEXP; ++e)
                s += (float)ec_p[l*160 + e*16] * rprob_p[l*160 + e*16];
        out[8192] = 10.0f * s / (4096.0f * 4096.0f);
    }
}

extern "C" void kernel_launch(void* const* d_in, const int* in_sizes, int n_in,
                              void* d_out, int out_size, void* d_ws, size_t ws_size,
                              hipStream_t stream) {
    const float* x        = (const float*)d_in[0];
    const float* conv_w   = (const float*)d_in[1];
    const float* conv_b   = (const float*)d_in[2];
    const float* pe       = (const float*)d_in[3];
    const float* ln0_g    = (const float*)d_in[4];
    const float* ln0_b    = (const float*)d_in[5];
    const float* wq       = (const float*)d_in[6];
    const float* bq       = (const float*)d_in[7];
    const float* wk       = (const float*)d_in[8];
    const float* bk       = (const float*)d_in[9];
    const float* wv       = (const float*)d_in[10];
    const float* bv       = (const float*)d_in[11];
    const float* wo       = (const float*)d_in[12];
    const float* bo       = (const float*)d_in[13];
    const float* ln1_g    = (const float*)d_in[14];
    const float* ln1_b    = (const float*)d_in[15];
    const float* ln2_g    = (const float*)d_in[16];
    const float* ln2_b    = (const float*)d_in[17];
    const float* router_w = (const float*)d_in[18];
    const float* router_b = (const float*)d_in[19];
    const float* e_w1     = (const float*)d_in[20];
    const float* e_b1     = (const float*)d_in[21];
    const float* e_w2     = (const float*)d_in[22];
    const float* e_b2     = (const float*)d_in[23];
    const float* deconv_w = (const float*)d_in[24];
    const float* deconv_b = (const float*)d_in[25];
    const float* lin1_w   = (const float*)d_in[26];
    const float* lin1_b   = (const float*)d_in[27];
    const float* lin2_w   = (const float*)d_in[28];
    const float* lin2_b   = (const float*)d_in[29];

    float* ws = (float*)d_ws;
    const size_t M = 1048576;
    float* z    = ws;
    unsigned short* qb  = (unsigned short*)(ws + 1*M);   // bf16 Q (pre-scaled)
    unsigned short* kb  = (unsigned short*)(ws + 2*M);   // bf16 K
    unsigned short* vtb = (unsigned short*)(ws + 3*M);   // bf16 V^T [bh][d][512]
    float* a    = ws + 4*M;
    float* rmax = ws + 6*M;
    float* rprob_p = rmax + 4096;             // 320 floats (16-stride padded)
    int* ec_p   = (int*)(rprob_p + 320);      // 320 ints (16-stride padded)
    int* elist  = ec_p + 320;                 // 2*10*4096
    unsigned short* wproj = (unsigned short*)(ws + 6*M + 98304);  // 8 x 65536 bf16 (1 MB)
    unsigned short* w1p = (unsigned short*)(ws + 1*M);  // per-layer packed over qb+kb (dead)
    unsigned short* w2p = (unsigned short*)(ws + 3*M);  // per-layer packed over vtb+a (dead)
    float* u    = ws + 1*M;                              // after layers
    unsigned short* wdp = (unsigned short*)(ws + 3*M);
    unsigned short* wl1 = (unsigned short*)(ws + 3*M + 131072 + 64);
    float* out  = (float*)d_out;

    zero_kernel<<<1, 512, 0, stream>>>(rprob_p, ec_p);
    {
        dim3 pg(32, 8);
        pack_proj<<<pg, 256, 0, stream>>>(wq, wk, wv, wo, wproj);
    }
    tokenizer_kernel<<<1024, 256, 0, stream>>>(x, conv_w, conv_b, pe, ln0_g, ln0_b, z);

    for (int l = 0; l < 2; ++l) {
        const unsigned short* wpl = wproj + (size_t)l*4*65536;
        dim3 qkvg(64, 3);
        proj_qkv<<<qkvg, 256, 0, stream>>>(z, wpl, bq + l*256, bk + l*256, bv + l*256,
                                           qb, kb, vtb);
        attn_mfma<<<256, 256, 0, stream>>>(qb, kb, vtb, a);
        proj_o_ln<<<64, 256, 0, stream>>>(a, wpl + 3*65536, bo + l*256, z,
                                          ln1_g + l*256, ln1_b + l*256);
        router_kernel<<<TTOT/RTOK, 512, 0, stream>>>(z, router_w + l*2560, router_b + l*10,
                                                     rmax, rprob_p + l*160, ec_p + l*160,
                                                     elist + l*10*TTOT);
        {
            dim3 pkg(1280, 2);
            pack_experts<<<pkg, 256, 0, stream>>>(e_w1 + (size_t)l*2621440,
                                                  e_w2 + (size_t)l*2621440, w1p, w2p);
        }
        dim3 mg(TTOT/TM, NEXP);
        moe_kernel<<<mg, 512, 0, stream>>>(z, elist + l*10*TTOT, ec_p + l*160, rmax,
                                           w1p, e_b1 + l*10240,
                                           w2p, e_b2 + l*2560,
                                           ln2_g + l*256, ln2_b + l*256);
    }

    pack_deconv_mfma<<<128, 256, 0, stream>>>(deconv_w, wdp);
    pack_lin1<<<16, 256, 0, stream>>>(lin1_w, wl1);
    deconv_mfma<<<128, 256, 0, stream>>>(z, wdp, deconv_b, u);
    head_mfma<<<128, 256, 0, stream>>>(u, wl1, lin1_b, lin2_w, lin2_b, out);
    loss_kernel<<<1, 64, 0, stream>>>(ec_p, rprob_p, out);
}

// Round 15
// 257.956 us; speedup vs baseline: 1.4003x; 1.0087x over previous
//
#include <hip/hip_runtime.h>
#include <math.h>

#define LATN 512
#define DN 256
#define DKN 128
#define TTOT 4096   // B*LAT
#define NEXP 10
#define DFFN 1024

using bf16x8 = __attribute__((ext_vector_type(8))) short;
using f32x4  = __attribute__((ext_vector_type(4))) float;

__device__ __forceinline__ float dot4(float4 a, float4 b) {
    return a.x*b.x + a.y*b.y + a.z*b.z + a.w*b.w;
}

__device__ __forceinline__ unsigned short f2bf(float f) {
    union { float f; unsigned int u; } v; v.f = f;
    unsigned int u = v.u + 0x7FFFu + ((v.u >> 16) & 1u);
    return (unsigned short)(u >> 16);
}

__device__ __forceinline__ float wave_sum(float x) {
    #pragma unroll
    for (int off = 32; off; off >>= 1) x += __shfl_xor(x, off, 64);
    return x;
}

// ---------------- zero init (padded counters) ----------------
__global__ void zero_kernel(float* rprob_p, int* ec_p) {
    int i = threadIdx.x;
    if (i < 320) { rprob_p[i] = 0.f; ec_p[i] = 0; }
}

// ---------------- tokenizer: wave-per-token, shfl-only LN ----------------
__global__ __launch_bounds__(256)
void tokenizer_kernel(const float* __restrict__ x, const float* __restrict__ cw,
                      const float* __restrict__ cb, const float* __restrict__ pe,
                      const float* __restrict__ g, const float* __restrict__ bb,
                      float* __restrict__ z) {
    int tid = threadIdx.x;
    int w = tid >> 6, l = tid & 63;
    int t = blockIdx.x*4 + w;
    int lt = t & (LATN - 1);
    int b = t >> 9;
    const float* xb = x + (size_t)b * 1024;
    int p0 = 2 * lt;
    float xv[6];
    #pragma unroll
    for (int i = 0; i < 6; ++i) {
        int p = min(max(p0 - 2 + i, 0), 1023);
        xv[i] = xb[p];
    }
    float v[4]; float s = 0.f, q = 0.f;
    #pragma unroll
    for (int c = 0; c < 4; ++c) {
        int d = l + 64*c;
        float w0 = cw[d*5+0], w1 = cw[d*5+1], w2 = cw[d*5+2], w3 = cw[d*5+3], w4 = cw[d*5+4];
        float bv = cb[d];
        float h0 = bv + w0*xv[0] + w1*xv[1] + w2*xv[2] + w3*xv[3] + w4*xv[4];
        float h1 = bv + w0*xv[1] + w1*xv[2] + w2*xv[3] + w3*xv[4] + w4*xv[5];
        float pool = sqrtf(h0*h0 + h1*h1);
        float val = pool + pe[lt*DN + d];
        v[c] = val; s += val; q += val*val;
    }
    s = wave_sum(s); q = wave_sum(q);
    float mu = s * (1.0f/DN);
    float var = q * (1.0f/DN) - mu*mu;
    float rs = rsqrtf(var + 1e-5f);
    #pragma unroll
    for (int c = 0; c < 4; ++c) {
        int d = l + 64*c;
        z[(size_t)t*DN + d] = (v[c] - mu)*rs*g[d] + bb[d];
    }
}

// ---------------- pack projection weights: fp32 [out,in] -> bf16 B-frag ----------
__global__ void pack_proj(const float* __restrict__ wq, const float* __restrict__ wk,
                          const float* __restrict__ wv, const float* __restrict__ wo,
                          unsigned short* __restrict__ wp) {
    int mat = blockIdx.y;              // 0..7 : layer*4 + {q,k,v,o}
    int l0 = mat >> 2, which = mat & 3;
    const float* base = (which == 0) ? wq : (which == 1) ? wk : (which == 2) ? wv : wo;
    const float* W = base + l0*65536;
    int tid = blockIdx.x*256 + threadIdx.x;   // 0..8191
    int l = tid & 63, kk = (tid >> 6) & 7, nt = tid >> 9;
    const float* src = W + (size_t)(nt*16 + (l&15))*DN + kk*32 + (l>>4)*8;
    unsigned short o[8];
    #pragma unroll
    for (int j = 0; j < 8; ++j) o[j] = f2bf(src[j]);
    *(ulonglong2*)(wp + (size_t)mat*65536 + (size_t)tid*8) = *(ulonglong2*)o;
}

// ---------------- MFMA projection GEMM body. OM: 1=bf16 out, 2=bf16 vT ----------
template<int OM>
__device__ __forceinline__ void proj_body(const float* __restrict__ A,
                                          const unsigned short* __restrict__ wpm,
                                          const float* __restrict__ bias,
                                          void* __restrict__ outp, int t0, float oscale,
                                          unsigned short* ts) {
    int tid = threadIdx.x;
    #pragma unroll
    for (int i = 0; i < 16; ++i) {
        int f4 = i*256 + tid;
        int row = f4 >> 6, c4 = f4 & 63;
        float4 a = *(const float4*)&A[(size_t)(t0+row)*DN + c4*4];
        ushort4 o = { f2bf(a.x), f2bf(a.y), f2bf(a.z), f2bf(a.w) };
        *(ushort4*)&ts[row*264 + c4*4] = o;
    }
    __syncthreads();
    int w = tid >> 6, l = tid & 63;
    f32x4 acc[4][4];
    #pragma unroll
    for (int m = 0; m < 4; ++m)
        #pragma unroll
        for (int n = 0; n < 4; ++n) acc[m][n] = (f32x4){0.f,0.f,0.f,0.f};
    const bf16x8* wv = (const bf16x8*)wpm;
    #pragma unroll
    for (int kk = 0; kk < 8; ++kk) {
        bf16x8 af[4];
        #pragma unroll
        for (int m = 0; m < 4; ++m)
            af[m] = *(const bf16x8*)&ts[(m*16 + (l&15))*264 + kk*32 + (l>>4)*8];
        #pragma unroll
        for (int n = 0; n < 4; ++n) {
            bf16x8 bf = wv[((w*4 + n)*8 + kk)*64 + l];
            #pragma unroll
            for (int m = 0; m < 4; ++m)
                acc[m][n] = __builtin_amdgcn_mfma_f32_16x16x32_bf16(af[m], bf, acc[m][n], 0, 0, 0);
        }
    }
    #pragma unroll
    for (int n = 0; n < 4; ++n) {
        int col = w*64 + n*16 + (l&15);
        float bv2 = bias[col];
        #pragma unroll
        for (int m = 0; m < 4; ++m) {
            #pragma unroll
            for (int r = 0; r < 4; ++r) {
                int row = t0 + m*16 + (l>>4)*4 + r;
                float val = acc[m][n][r] + bv2;
                if (OM == 1)
                    ((unsigned short*)outp)[(size_t)row*DN + col] = f2bf(val * oscale);
                else
                    ((unsigned short*)outp)[(((size_t)(row>>9)*2 + (col>>7))*128 + (col&127))*512 + (row&511)] = f2bf(val);
            }
        }
    }
}

__global__ __launch_bounds__(256)
void proj_qkv(const float* __restrict__ z, const unsigned short* __restrict__ wp,
              const float* __restrict__ bq, const float* __restrict__ bk,
              const float* __restrict__ bv,
              unsigned short* __restrict__ qb, unsigned short* __restrict__ kb,
              unsigned short* __restrict__ vtb) {
    __shared__ unsigned short ts[64*264];
    int mat = blockIdx.y;
    if (mat == 0)      proj_body<1>(z, wp,          bq, qb,  blockIdx.x*64, 0.08838834764831844f, ts);
    else if (mat == 1) proj_body<1>(z, wp + 65536,  bk, kb,  blockIdx.x*64, 1.0f, ts);
    else               proj_body<2>(z, wp + 131072, bv, vtb, blockIdx.x*64, 1.0f, ts);
}

// ---------------- out-proj + residual + LN fused (writes z in place) ------------
__global__ __launch_bounds__(256)
void proj_o_ln(const float* __restrict__ A, const unsigned short* __restrict__ wpm,
               const float* __restrict__ bias, float* __restrict__ z,
               const float* __restrict__ lng, const float* __restrict__ lnb) {
    __shared__ unsigned short ts[64*264];
    __shared__ float wsum[4][64], wsq[4][64];
    int t0 = blockIdx.x * 64;
    int tid = threadIdx.x;
    #pragma unroll
    for (int i = 0; i < 16; ++i) {
        int f4 = i*256 + tid;
        int row = f4 >> 6, c4 = f4 & 63;
        float4 a = *(const float4*)&A[(size_t)(t0+row)*DN + c4*4];
        ushort4 o = { f2bf(a.x), f2bf(a.y), f2bf(a.z), f2bf(a.w) };
        *(ushort4*)&ts[row*264 + c4*4] = o;
    }
    __syncthreads();
    int w = tid >> 6, l = tid & 63, c = l & 15, g = l >> 4;
    f32x4 acc[4][4];
    #pragma unroll
    for (int m = 0; m < 4; ++m)
        #pragma unroll
        for (int n = 0; n < 4; ++n) acc[m][n] = (f32x4){0.f,0.f,0.f,0.f};
    const bf16x8* wv = (const bf16x8*)wpm;
    #pragma unroll
    for (int kk = 0; kk < 8; ++kk) {
        bf16x8 af[4];
        #pragma unroll
        for (int m = 0; m < 4; ++m)
            af[m] = *(const bf16x8*)&ts[(m*16 + c)*264 + kk*32 + g*8];
        #pragma unroll
        for (int n = 0; n < 4; ++n) {
            bf16x8 bf = wv[((w*4 + n)*8 + kk)*64 + l];
            #pragma unroll
            for (int m = 0; m < 4; ++m)
                acc[m][n] = __builtin_amdgcn_mfma_f32_16x16x32_bf16(af[m], bf, acc[m][n], 0, 0, 0);
        }
    }
    float vals[4][4][4];
    float sm[4][4], sq[4][4];
    #pragma unroll
    for (int m = 0; m < 4; ++m)
        #pragma unroll
        for (int r = 0; r < 4; ++r) { sm[m][r] = 0.f; sq[m][r] = 0.f; }
    #pragma unroll
    for (int n = 0; n < 4; ++n) {
        int col = w*64 + n*16 + c;
        float bv2 = bias[col];
        #pragma unroll
        for (int m = 0; m < 4; ++m)
            #pragma unroll
            for (int r = 0; r < 4; ++r) {
                int row = t0 + m*16 + g*4 + r;
                float v = acc[m][n][r] + bv2 + z[(size_t)row*DN + col];
                vals[m][n][r] = v;
                sm[m][r] += v; sq[m][r] += v*v;
            }
    }
    #pragma unroll
    for (int m = 0; m < 4; ++m)
        #pragma unroll
        for (int r = 0; r < 4; ++r) {
            #pragma unroll
            for (int off = 1; off <= 8; off <<= 1) {
                sm[m][r] += __shfl_xor(sm[m][r], off, 64);
                sq[m][r] += __shfl_xor(sq[m][r], off, 64);
            }
        }
    if (c == 0) {
        #pragma unroll
        for (int m = 0; m < 4; ++m)
            #pragma unroll
            for (int r = 0; r < 4; ++r) {
                wsum[w][m*16 + g*4 + r] = sm[m][r];
                wsq[w][m*16 + g*4 + r] = sq[m][r];
            }
    }
    __syncthreads();
    #pragma unroll
    for (int m = 0; m < 4; ++m)
        #pragma unroll
        for (int r = 0; r < 4; ++r) {
            int rl = m*16 + g*4 + r;
            float S = wsum[0][rl] + wsum[1][rl] + wsum[2][rl] + wsum[3][rl];
            float Q = wsq[0][rl] + wsq[1][rl] + wsq[2][rl] + wsq[3][rl];
            float mu = S * (1.0f/DN);
            float var = Q * (1.0f/DN) - mu*mu;
            float rs = rsqrtf(var + 1e-5f);
            int row = t0 + rl;
            #pragma unroll
            for (int n = 0; n < 4; ++n) {
                int col = w*64 + n*16 + c;
                z[(size_t)row*DN + col] = (vals[m][n][r] - mu)*rs*lng[col] + lnb[col];
            }
        }
}

// ---------------- MFMA attention: swapped QK^T (S^T), in-reg softmax, PV via LDS-P
__global__ __launch_bounds__(256)
void attn_mfma(const unsigned short* __restrict__ qb, const unsigned short* __restrict__ kb,
               const unsigned short* __restrict__ vtb, float* __restrict__ a) {
    int blk = blockIdx.x;
    int xcd = blk & 7, idx = blk >> 3;
    int bh = xcd*2 + (idx & 1);        // 2 bh per XCD -> 1 MB L2 working set
    int qt = idx >> 1;
    int b = bh >> 1, h = bh & 1;
    int q0 = qt * 32;
    int tid = threadIdx.x;
    int w = tid >> 6, l = tid & 63;
    int c = l & 15, g = l >> 4;

    __shared__ __align__(16) unsigned short p_lds[32*512];  // [q][key] bf16, XOR-swizzled
    __shared__ float smax[4][2][16];
    __shared__ float ssum[4][2][16];

    bf16x8 qf_[2][4];
    #pragma unroll
    for (int qf = 0; qf < 2; ++qf)
        #pragma unroll
        for (int kk = 0; kk < 4; ++kk)
            qf_[qf][kk] = *(const bf16x8*)&qb[((size_t)(b*LATN + q0 + qf*16 + c))*DN + h*DKN + kk*32 + g*8];

    f32x4 st[8][2];
    #pragma unroll
    for (int f = 0; f < 8; ++f) { st[f][0] = (f32x4){0,0,0,0}; st[f][1] = (f32x4){0,0,0,0}; }
    #pragma unroll
    for (int f = 0; f < 8; ++f) {
        int kbase = w*128 + f*16;
        bf16x8 kf[4];
        #pragma unroll
        for (int kk = 0; kk < 4; ++kk)
            kf[kk] = *(const bf16x8*)&kb[((size_t)(b*LATN + kbase + c))*DN + h*DKN + kk*32 + g*8];
        #pragma unroll
        for (int kk = 0; kk < 4; ++kk) {
            st[f][0] = __builtin_amdgcn_mfma_f32_16x16x32_bf16(kf[kk], qf_[0][kk], st[f][0], 0, 0, 0);
            st[f][1] = __builtin_amdgcn_mfma_f32_16x16x32_bf16(kf[kk], qf_[1][kk], st[f][1], 0, 0, 0);
        }
    }

    float gmax[2], ginv[2];
    #pragma unroll
    for (int qf = 0; qf < 2; ++qf) {
        float m = -1e30f;
        #pragma unroll
        for (int f = 0; f < 8; ++f)
            #pragma unroll
            for (int r = 0; r < 4; ++r) m = fmaxf(m, st[f][qf][r]);
        m = fmaxf(m, __shfl_xor(m, 16, 64));
        m = fmaxf(m, __shfl_xor(m, 32, 64));
        if (l < 16) smax[w][qf][l] = m;
    }
    __syncthreads();
    #pragma unroll
    for (int qf = 0; qf < 2; ++qf)
        gmax[qf] = fmaxf(fmaxf(smax[0][qf][c], smax[1][qf][c]),
                         fmaxf(smax[2][qf][c], smax[3][qf][c]));
    #pragma unroll
    for (int qf = 0; qf < 2; ++qf) {
        float s = 0.f;
        #pragma unroll
        for (int f = 0; f < 8; ++f)
            #pragma unroll
            for (int r = 0; r < 4; ++r) {
                float e = __expf(st[f][qf][r] - gmax[qf]);
                st[f][qf][r] = e; s += e;
            }
        s += __shfl_xor(s, 16, 64);
        s += __shfl_xor(s, 32, 64);
        if (l < 16) ssum[w][qf][l] = s;
    }
    __syncthreads();
    #pragma unroll
    for (int qf = 0; qf < 2; ++qf)
        ginv[qf] = 1.0f / (ssum[0][qf][c] + ssum[1][qf][c] + ssum[2][qf][c] + ssum[3][qf][c]);

    #pragma unroll
    for (int qf = 0; qf < 2; ++qf) {
        int q_ = qf*16 + c;
        int rowb = q_ * 1024;
        int swz = (q_ & 7) << 4;
        float iv = ginv[qf];
        #pragma unroll
        for (int f = 0; f < 8; ++f) {
            unsigned int lo = (unsigned int)f2bf(st[f][qf][0]*iv) |
                              ((unsigned int)f2bf(st[f][qf][1]*iv) << 16);
            unsigned int hi = (unsigned int)f2bf(st[f][qf][2]*iv) |
                              ((unsigned int)f2bf(st[f][qf][3]*iv) << 16);
            int key0 = w*128 + f*16 + g*4;
            *(unsigned long long*)((char*)p_lds + rowb + ((key0*2) ^ swz)) =
                (unsigned long long)lo | ((unsigned long long)hi << 32);
        }
    }
    __syncthreads();

    f32x4 o[2][2];
    o[0][0] = (f32x4){0,0,0,0}; o[0][1] = (f32x4){0,0,0,0};
    o[1][0] = (f32x4){0,0,0,0}; o[1][1] = (f32x4){0,0,0,0};
    #pragma unroll
    for (int kk = 0; kk < 16; ++kk) {
        bf16x8 pb[2];
        #pragma unroll
        for (int qf = 0; qf < 2; ++qf) {
            int q_ = qf*16 + c;
            pb[qf] = *(const bf16x8*)((const char*)p_lds + q_*1024 +
                                      (((kk*32 + g*8)*2) ^ ((q_&7)<<4)));
        }
        bf16x8 va[2];
        #pragma unroll
        for (int m = 0; m < 2; ++m)
            va[m] = *(const bf16x8*)&vtb[((size_t)(bh*128 + w*32 + m*16 + c))*512 + kk*32 + g*8];
        #pragma unroll
        for (int m = 0; m < 2; ++m) {
            o[m][0] = __builtin_amdgcn_mfma_f32_16x16x32_bf16(va[m], pb[0], o[m][0], 0, 0, 0);
            o[m][1] = __builtin_amdgcn_mfma_f32_16x16x32_bf16(va[m], pb[1], o[m][1], 0, 0, 0);
        }
    }
    #pragma unroll
    for (int m = 0; m < 2; ++m)
        #pragma unroll
        for (int qf = 0; qf < 2; ++qf)
            #pragma unroll
            for (int r = 0; r < 4; ++r) {
                int d = w*32 + m*16 + g*4 + r;
                a[((size_t)(b*LATN + q0 + qf*16 + c))*DN + h*DKN + d] = o[m][qf][r];
            }
}

// ---------------- router: 32 tokens/block, block-aggregated padded atomics ----
#define RTOK 32
__global__ __launch_bounds__(512)
void router_kernel(const float* __restrict__ z, const float* __restrict__ rw,
                   const float* __restrict__ rb, float* __restrict__ rmaxv,
                   float* __restrict__ rprob_p, int* __restrict__ ec_p,
                   int* __restrict__ elist) {
    __shared__ float rws[NEXP*DN];
    __shared__ float sprob[NEXP];
    __shared__ int lcnt[NEXP], lbase[NEXP];
    __shared__ int lrank[RTOK];
    __shared__ int lam[RTOK];
    int tid = threadIdx.x;
    for (int i = tid; i < NEXP*DN; i += 512) rws[i] = rw[i];
    if (tid < NEXP) { sprob[tid] = 0.f; lcnt[tid] = 0; }
    __syncthreads();
    int g = tid >> 4, j = tid & 15;
    int t = blockIdx.x * RTOK + g;
    const float4* z4 = (const float4*)&z[(size_t)t*DN + j*16];
    const float4* rws4 = (const float4*)rws;
    float acc[NEXP];
    #pragma unroll
    for (int e = 0; e < NEXP; ++e) acc[e] = 0.f;
    int r0 = (j >> 1) & 3;
    #pragma unroll
    for (int kq = 0; kq < 4; ++kq) {
        int k4 = (kq + r0) & 3;
        float4 zv = z4[k4];
        #pragma unroll
        for (int e = 0; e < NEXP; ++e)
            acc[e] += dot4(zv, rws4[e*64 + j*4 + k4]);
    }
    #pragma unroll
    for (int e = 0; e < NEXP; ++e) {
        acc[e] += __shfl_xor(acc[e], 1, 64);
        acc[e] += __shfl_xor(acc[e], 2, 64);
        acc[e] += __shfl_xor(acc[e], 4, 64);
        acc[e] += __shfl_xor(acc[e], 8, 64);
    }
    if (j == 0) {
        float lg[NEXP];
        float m = acc[0] + rb[0]; int am = 0;
        lg[0] = m;
        #pragma unroll
        for (int e = 1; e < NEXP; ++e) {
            lg[e] = acc[e] + rb[e];
            if (lg[e] > m) { m = lg[e]; am = e; }
        }
        float p[NEXP], s = 0.f;
        #pragma unroll
        for (int e = 0; e < NEXP; ++e) { p[e] = expf(lg[e] - m); s += p[e]; }
        float inv = 1.0f / s;
        rmaxv[t] = p[am] * inv;
        lam[g] = am;
        lrank[g] = atomicAdd(&lcnt[am], 1);             // LDS atomic
        #pragma unroll
        for (int e = 0; e < NEXP; ++e) atomicAdd(&sprob[e], p[e] * inv);  // LDS atomic
    }
    __syncthreads();
    if (tid < NEXP) {
        lbase[tid] = atomicAdd(&ec_p[tid*16], lcnt[tid]);   // padded: 1 line/expert
        atomicAdd(&rprob_p[tid*16], sprob[tid]);            // padded: 1 line/expert
    }
    __syncthreads();
    if (j == 0)
        elist[lam[g]*TTOT + lbase[lam[g]] + lrank[g]] = t;
}

// ---------------- pack expert weights (merged): fp32 -> bf16 B-frag --------------
__global__ void pack_experts(const float* __restrict__ w1l, const float* __restrict__ w2l,
                             unsigned short* __restrict__ w1p, unsigned short* __restrict__ w2p) {
    int tid = blockIdx.x*256 + threadIdx.x;   // 327680 per matrix set
    unsigned short o[8];
    if (blockIdx.y == 0) {
        int l = tid & 63, kk = (tid >> 6) & 7, nt = (tid >> 9) & 63, e = tid >> 15;
        const float* src = w1l + (size_t)e*262144 + (size_t)(kk*32 + (l>>4)*8)*DFFN + nt*16 + (l&15);
        #pragma unroll
        for (int j = 0; j < 8; ++j) o[j] = f2bf(src[(size_t)j*DFFN]);
        *(ulonglong2*)(w1p + (size_t)tid*8) = *(ulonglong2*)o;
    } else {
        int l = tid & 63, kk = (tid >> 6) & 31, nt = (tid >> 11) & 15, e = tid >> 15;
        const float* src = w2l + (size_t)e*262144 + (size_t)(kk*32 + (l>>4)*8)*DN + nt*16 + (l&15);
        #pragma unroll
        for (int j = 0; j < 8; ++j) o[j] = f2bf(src[(size_t)j*DN]);
        *(ulonglong2*)(w2p + (size_t)tid*8) = *(ulonglong2*)o;
    }
}

// ---------------- MoE: TM=16, 2D grid, 8 waves/block (round-14 config) -----------
#define TM 16
__global__ __launch_bounds__(512)
void moe_kernel(float* __restrict__ z, const int* __restrict__ elist,
                const int* __restrict__ ec_p, const float* __restrict__ rmaxv,
                const unsigned short* __restrict__ w1p, const float* __restrict__ b1,
                const unsigned short* __restrict__ w2p, const float* __restrict__ b2,
                const float* __restrict__ g, const float* __restrict__ bb) {
    int e = blockIdx.y;
    int cnt = ec_p[e*16];
    int base = blockIdx.x * TM;
    if (base >= cnt) return;
    int n = min(TM, cnt - base);

    __shared__ __align__(16) unsigned short ts[16*264];
    __shared__ __align__(16) unsigned short hbuf[16*1032];
    __shared__ __align__(16) float ybuf[16*260];
    __shared__ int toks[16];
    __shared__ float rm[16];

    int tid = threadIdx.x;
    int w = tid >> 6, l = tid & 63, c = l & 15, gq = l >> 4;
    if (tid < 16) {
        int tt = (tid < n) ? elist[e*TTOT + base + tid] : 0;
        toks[tid] = tt;
        rm[tid] = rmaxv[tt];
    }
    __syncthreads();
    {
        int half = tid >> 8, colx = tid & 255;
        #pragma unroll
        for (int m = 0; m < 8; ++m)
            ts[(half*8 + m)*264 + colx] = f2bf(z[(size_t)toks[half*8 + m]*DN + colx]);
    }
    __syncthreads();

    const bf16x8* w1v = (const bf16x8*)w1p;
    const float* b1e = b1 + e*DFFN;
    f32x4 acc[8];
    #pragma unroll
    for (int i = 0; i < 8; ++i) acc[i] = (f32x4){0.f,0.f,0.f,0.f};
    #pragma unroll
    for (int kk = 0; kk < 8; ++kk) {
        bf16x8 a = *(const bf16x8*)(ts + c*264 + kk*32 + gq*8);
        const bf16x8* wbp = w1v + (((size_t)e*64 + w*8)*8 + kk)*64 + l;
        #pragma unroll
        for (int nt2 = 0; nt2 < 8; ++nt2)
            acc[nt2] = __builtin_amdgcn_mfma_f32_16x16x32_bf16(a, wbp[nt2*512], acc[nt2], 0, 0, 0);
    }
    #pragma unroll
    for (int nt2 = 0; nt2 < 8; ++nt2) {
        int col = w*128 + nt2*16 + c;
        float bv = b1e[col];
        #pragma unroll
        for (int r = 0; r < 4; ++r) {
            int row = gq*4 + r;
            hbuf[row*1032 + col] = f2bf(fmaxf(acc[nt2][r] + bv, 0.f));
        }
    }
    __syncthreads();

    const bf16x8* w2v = (const bf16x8*)w2p;
    const float* b2e = b2 + e*DN;
    f32x4 acc2[2];
    acc2[0] = (f32x4){0.f,0.f,0.f,0.f};
    acc2[1] = (f32x4){0.f,0.f,0.f,0.f};
    for (int kk = 0; kk < 32; ++kk) {
        bf16x8 a = *(const bf16x8*)(hbuf + c*1032 + kk*32 + gq*8);
        const bf16x8* wbp = w2v + (((size_t)e*16 + w*2)*32 + kk)*64 + l;
        acc2[0] = __builtin_amdgcn_mfma_f32_16x16x32_bf16(a, wbp[0], acc2[0], 0, 0, 0);
        acc2[1] = __builtin_amdgcn_mfma_f32_16x16x32_bf16(a, wbp[2048], acc2[1], 0, 0, 0);
    }
    #pragma unroll
    for (int nt2 = 0; nt2 < 2; ++nt2) {
        int col = w*32 + nt2*16 + c;
        float bv = b2e[col];
        #pragma unroll
        for (int r = 0; r < 4; ++r) {
            int row = gq*4 + r;
            ybuf[row*260 + col] = (acc2[nt2][r] + bv) * rm[row];
        }
    }
    __syncthreads();

    #pragma unroll
    for (int rr = 0; rr < 2; ++rr) {
        int row = w*2 + rr;
        if (row < n) {
            int t = toks[row];
            float v[4];
            #pragma unroll
            for (int cc = 0; cc < 4; ++cc)
                v[cc] = ybuf[row*260 + l + 64*cc] + z[(size_t)t*DN + l + 64*cc];
            float s = wave_sum(v[0]+v[1]+v[2]+v[3]);
            float mu = s * (1.0f/DN);
            float s2 = 0.f;
            #pragma unroll
            for (int cc = 0; cc < 4; ++cc) { v[cc] -= mu; s2 += v[cc]*v[cc]; }
            s2 = wave_sum(s2);
            float rs = rsqrtf(s2 * (1.0f/DN) + 1e-5f);
            #pragma unroll
            for (int cc = 0; cc < 4; ++cc) {
                int col = l + 64*cc;
                z[(size_t)t*DN + col] = v[cc]*rs*g[col] + bb[col];
            }
        }
    }
}

// ---------------- pack tail weights: deconv taps + lin1 (merged) -----------------
__global__ void pack_tail(const float* __restrict__ w, const float* __restrict__ l1w,
                          unsigned short* __restrict__ wdp, unsigned short* __restrict__ wl1) {
    int bid = blockIdx.x;
    unsigned short o[8];
    if (bid < 128) {
        int tid = bid*256 + threadIdx.x;   // 32768
        int l = tid & 63, kk = (tid >> 6) & 7, nt = (tid >> 9) & 15, tap = tid >> 13;
        int dout = nt*16 + (l&15);
        int din0 = kk*32 + (l>>4)*8;
        #pragma unroll
        for (int j = 0; j < 8; ++j)
            o[j] = f2bf(w[((size_t)(din0 + j)*DN + dout)*4 + tap]);
        *(ulonglong2*)(wdp + (size_t)tid*8) = *(ulonglong2*)o;
    } else {
        int tid = (bid - 128)*256 + threadIdx.x;   // 4096
        int l = tid & 63, kk = (tid >> 6) & 7, nt = tid >> 9;
        const float* src = l1w + (size_t)(nt*16 + (l&15))*DN + kk*32 + (l>>4)*8;
        #pragma unroll
        for (int j = 0; j < 8; ++j) o[j] = f2bf(src[j]);
        *(ulonglong2*)(wl1 + (size_t)tid*8) = *(ulonglong2*)o;
    }
}

// ---------------- fused deconv (MFMA) + head (lin1+tanh+lin2) --------------------
__global__ __launch_bounds__(256)
void deconv_head(const float* __restrict__ z, const unsigned short* __restrict__ wdp,
                 const float* __restrict__ db, const unsigned short* __restrict__ wl1,
                 const float* __restrict__ hb1, const float* __restrict__ hw2,
                 const float* __restrict__ hb2, float* __restrict__ out) {
    int blk = blockIdx.x;
    int b = blk >> 4, lt = blk & 15;
    int l0 = lt * 32;
    __shared__ __align__(16) unsigned short zs[34*264];
    __shared__ __align__(16) unsigned short us[64*264];
    __shared__ float part[4][64];
    int tid = threadIdx.x;
    // ---- stage z rows [l0-1, l0+33)
    #pragma unroll
    for (int i = 0; i < 9; ++i) {
        int f4 = i*256 + tid;
        if (f4 < 34*64) {
            int row = f4 >> 6, c4 = f4 & 63;
            int l = l0 - 1 + row;
            float4 a = (l >= 0 && l < LATN)
                ? *(const float4*)&z[((size_t)b*LATN + l)*DN + c4*4]
                : make_float4(0.f, 0.f, 0.f, 0.f);
            ushort4 o = { f2bf(a.x), f2bf(a.y), f2bf(a.z), f2bf(a.w) };
            *(ushort4*)&zs[row*264 + c4*4] = o;
        }
    }
    __syncthreads();
    int w = tid >> 6, l = tid & 63;
    // ---- deconv MFMA
    f32x4 acce[2][4], acco[2][4];
    #pragma unroll
    for (int m = 0; m < 2; ++m)
        #pragma unroll
        for (int n = 0; n < 4; ++n) {
            acce[m][n] = (f32x4){0.f,0.f,0.f,0.f};
            acco[m][n] = (f32x4){0.f,0.f,0.f,0.f};
        }
    const bf16x8* wdv = (const bf16x8*)wdp;
    #pragma unroll
    for (int kk = 0; kk < 8; ++kk) {
        bf16x8 a0[2], a1[2], a2[2];
        #pragma unroll
        for (int m = 0; m < 2; ++m) {
            int rb = (m*16 + (l&15))*264 + kk*32 + (l>>4)*8;
            a0[m] = *(const bf16x8*)&zs[rb];
            a1[m] = *(const bf16x8*)&zs[rb + 264];
            a2[m] = *(const bf16x8*)&zs[rb + 528];
        }
        #pragma unroll
        for (int n = 0; n < 4; ++n) {
            int nt = w*4 + n;
            bf16x8 bt0 = wdv[((0*16 + nt)*8 + kk)*64 + l];
            bf16x8 bt1 = wdv[((1*16 + nt)*8 + kk)*64 + l];
            bf16x8 bt2 = wdv[((2*16 + nt)*8 + kk)*64 + l];
            bf16x8 bt3 = wdv[((3*16 + nt)*8 + kk)*64 + l];
            #pragma unroll
            for (int m = 0; m < 2; ++m) {
                acco[m][n] = __builtin_amdgcn_mfma_f32_16x16x32_bf16(a2[m], bt0, acco[m][n], 0, 0, 0);
                acce[m][n] = __builtin_amdgcn_mfma_f32_16x16x32_bf16(a1[m], bt1, acce[m][n], 0, 0, 0);
                acco[m][n] = __builtin_amdgcn_mfma_f32_16x16x32_bf16(a1[m], bt2, acco[m][n], 0, 0, 0);
                acce[m][n] = __builtin_amdgcn_mfma_f32_16x16x32_bf16(a0[m], bt3, acce[m][n], 0, 0, 0);
            }
        }
    }
    // ---- u tile (64 rows x 256 cols) -> bf16 LDS (with deconv bias)
    #pragma unroll
    for (int n = 0; n < 4; ++n) {
        int col = (w*4 + n)*16 + (l&15);
        float bv = db[col];
        #pragma unroll
        for (int m = 0; m < 2; ++m) {
            #pragma unroll
            for (int r = 0; r < 4; ++r) {
                int rt = m*16 + (l>>4)*4 + r;
                us[(2*rt)*264 + col]     = f2bf(acce[m][n][r] + bv);
                us[(2*rt + 1)*264 + col] = f2bf(acco[m][n][r] + bv);
            }
        }
    }
    __syncthreads();
    // ---- head: lin1 MFMA + tanh*lin2 + reduce
    f32x4 hacc[4][2];
    #pragma unroll
    for (int m = 0; m < 4; ++m) { hacc[m][0] = (f32x4){0.f,0.f,0.f,0.f}; hacc[m][1] = (f32x4){0.f,0.f,0.f,0.f}; }
    const bf16x8* wv1 = (const bf16x8*)wl1;
    #pragma unroll
    for (int kk = 0; kk < 8; ++kk) {
        bf16x8 af[4];
        #pragma unroll
        for (int m = 0; m < 4; ++m)
            af[m] = *(const bf16x8*)&us[(m*16 + (l&15))*264 + kk*32 + (l>>4)*8];
        #pragma unroll
        for (int n = 0; n < 2; ++n) {
            bf16x8 bf = wv1[((w*2 + n)*8 + kk)*64 + l];
            #pragma unroll
            for (int m = 0; m < 4; ++m)
                hacc[m][n] = __builtin_amdgcn_mfma_f32_16x16x32_bf16(af[m], bf, hacc[m][n], 0, 0, 0);
        }
    }
    float pm[4][4];
    #pragma unroll
    for (int m = 0; m < 4; ++m)
        #pragma unroll
        for (int r = 0; r < 4; ++r) pm[m][r] = 0.f;
    #pragma unroll
    for (int n = 0; n < 2; ++n) {
        int col = (w*2 + n)*16 + (l&15);
        float bb1 = hb1[col], ww2 = hw2[col];
        #pragma unroll
        for (int m = 0; m < 4; ++m)
            #pragma unroll
            for (int r = 0; r < 4; ++r)
                pm[m][r] += tanhf(hacc[m][n][r] + bb1) * ww2;
    }
    #pragma unroll
    for (int off = 1; off <= 8; off <<= 1)
        #pragma unroll
        for (int m = 0; m < 4; ++m)
            #pragma unroll
            for (int r = 0; r < 4; ++r)
                pm[m][r] += __shfl_xor(pm[m][r], off, 64);
    if ((l & 15) == 0) {
        #pragma unroll
        for (int m = 0; m < 4; ++m)
            #pragma unroll
            for (int r = 0; r < 4; ++r)
                part[w][m*16 + (l>>4)*4 + r] = pm[m][r];
    }
    __syncthreads();
    if (tid < 64)
        out[blk*64 + tid] = part[0][tid] + part[1][tid] + part[2][tid] + part[3][tid] + hb2[0];
}

// ---------------- loss ----------------
__global__ void loss_kernel(const int* __restrict__ ec_p, const float* __restrict__ rprob_p,
                            float* __restrict__ out) {
    if (threadIdx.x == 0) {
        float s = 0;
        for (int l = 0; l < 2; ++l)
            for (int e = 0; e < NEXP; ++e)
                s += (float)ec_p[l*160 + e*16] * rprob_p[l*160 + e*16];
        out[8192] = 10.0f * s / (4096.0f * 4096.0f);
    }
}

extern "C" void kernel_launch(void* const* d_in, const int* in_sizes, int n_in,
                              void* d_out, int out_size, void* d_ws, size_t ws_size,
                              hipStream_t stream) {
    const float* x        = (const float*)d_in[0];
    const float* conv_w   = (const float*)d_in[1];
    const float* conv_b   = (const float*)d_in[2];
    const float* pe       = (const float*)d_in[3];
    const float* ln0_g    = (const float*)d_in[4];
    const float* ln0_b    = (const float*)d_in[5];
    const float* wq       = (const float*)d_in[6];
    const float* bq       = (const float*)d_in[7];
    const float* wk       = (const float*)d_in[8];
    const float* bk       = (const float*)d_in[9];
    const float* wv       = (const float*)d_in[10];
    const float* bv       = (const float*)d_in[11];
    const float* wo       = (const float*)d_in[12];
    const float* bo       = (const float*)d_in[13];
    const float* ln1_g    = (const float*)d_in[14];
    const float* ln1_b    = (const float*)d_in[15];
    const float* ln2_g    = (const float*)d_in[16];
    const float* ln2_b    = (const float*)d_in[17];
    const float* router_w = (const float*)d_in[18];
    const float* router_b = (const float*)d_in[19];
    const float* e_w1     = (const float*)d_in[20];
    const float* e_b1     = (const float*)d_in[21];
    const float* e_w2     = (const float*)d_in[22];
    const float* e_b2     = (const float*)d_in[23];
    const float* deconv_w = (const float*)d_in[24];
    const float* deconv_b = (const float*)d_in[25];
    const float* lin1_w   = (const float*)d_in[26];
    const float* lin1_b   = (const float*)d_in[27];
    const float* lin2_w   = (const float*)d_in[28];
    const float* lin2_b   = (const float*)d_in[29];

    float* ws = (float*)d_ws;
    const size_t M = 1048576;
    float* z    = ws;
    unsigned short* qb  = (unsigned short*)(ws + 1*M);   // bf16 Q (pre-scaled)
    unsigned short* kb  = (unsigned short*)(ws + 2*M);   // bf16 K
    unsigned short* vtb = (unsigned short*)(ws + 3*M);   // bf16 V^T [bh][d][512]
    float* a    = ws + 4*M;
    float* rmax = ws + 6*M;
    float* rprob_p = rmax + 4096;             // 320 floats (16-stride padded)
    int* ec_p   = (int*)(rprob_p + 320);      // 320 ints (16-stride padded)
    int* elist  = ec_p + 320;                 // 2*10*4096
    unsigned short* wproj = (unsigned short*)(ws + 6*M + 98304);  // 8 x 65536 bf16 (1 MB)
    unsigned short* w1p = (unsigned short*)(ws + 1*M);  // per-layer packed over qb+kb (dead)
    unsigned short* w2p = (unsigned short*)(ws + 3*M);  // per-layer packed over vtb+a (dead)
    unsigned short* wdp = (unsigned short*)(ws + 3*M);
    unsigned short* wl1 = (unsigned short*)(ws + 3*M + 131072 + 64);
    float* out  = (float*)d_out;

    zero_kernel<<<1, 512, 0, stream>>>(rprob_p, ec_p);
    {
        dim3 pg(32, 8);
        pack_proj<<<pg, 256, 0, stream>>>(wq, wk, wv, wo, wproj);
    }
    tokenizer_kernel<<<1024, 256, 0, stream>>>(x, conv_w, conv_b, pe, ln0_g, ln0_b, z);

    for (int l = 0; l < 2; ++l) {
        const unsigned short* wpl = wproj + (size_t)l*4*65536;
        dim3 qkvg(64, 3);
        proj_qkv<<<qkvg, 256, 0, stream>>>(z, wpl, bq + l*256, bk + l*256, bv + l*256,
                                           qb, kb, vtb);
        attn_mfma<<<256, 256, 0, stream>>>(qb, kb, vtb, a);
        proj_o_ln<<<64, 256, 0, stream>>>(a, wpl + 3*65536, bo + l*256, z,
                                          ln1_g + l*256, ln1_b + l*256);
        router_kernel<<<TTOT/RTOK, 512, 0, stream>>>(z, router_w + l*2560, router_b + l*10,
                                                     rmax, rprob_p + l*160, ec_p + l*160,
                                                     elist + l*10*TTOT);
        {
            dim3 pkg(1280, 2);
            pack_experts<<<pkg, 256, 0, stream>>>(e_w1 + (size_t)l*2621440,
                                                  e_w2 + (size_t)l*2621440, w1p, w2p);
        }
        dim3 mg(TTOT/TM, NEXP);
        moe_kernel<<<mg, 512, 0, stream>>>(z, elist + l*10*TTOT, ec_p + l*160, rmax,
                                           w1p, e_b1 + l*10240,
                                           w2p, e_b2 + l*2560,
                                           ln2_g + l*256, ln2_b + l*256);
    }

    pack_tail<<<144, 256, 0, stream>>>(deconv_w, lin1_w, wdp, wl1);
    deconv_head<<<128, 256, 0, stream>>>(z, wdp, deconv_b, wl1,
                                         lin1_b, lin2_w, lin2_b, out);
    loss_kernel<<<1, 64, 0, stream>>>(ec_p, rprob_p, out);
}

// Round 16
// 227.947 us; speedup vs baseline: 1.5847x; 1.1317x over previous
//
#include <hip/hip_runtime.h>
#include <math.h>

#define LATN 512
#define DN 256
#define DKN 128
#define TTOT 4096   // B*LAT
#define NEXP 10
#define DFFN 1024

using bf16x8 = __attribute__((ext_vector_type(8))) short;
using f32x4  = __attribute__((ext_vector_type(4))) float;

__device__ __forceinline__ float dot4(float4 a, float4 b) {
    return a.x*b.x + a.y*b.y + a.z*b.z + a.w*b.w;
}

__device__ __forceinline__ unsigned short f2bf(float f) {
    union { float f; unsigned int u; } v; v.f = f;
    unsigned int u = v.u + 0x7FFFu + ((v.u >> 16) & 1u);
    return (unsigned short)(u >> 16);
}

__device__ __forceinline__ float wave_sum(float x) {
    #pragma unroll
    for (int off = 32; off; off >>= 1) x += __shfl_xor(x, off, 64);
    return x;
}

// ---------------- zero init (padded counters) ----------------
__global__ void zero_kernel(float* rprob_p, int* ec_p) {
    int i = threadIdx.x;
    if (i < 320) { rprob_p[i] = 0.f; ec_p[i] = 0; }
}

// ---------------- tokenizer: wave-per-token, shfl-only LN ----------------
__global__ __launch_bounds__(256)
void tokenizer_kernel(const float* __restrict__ x, const float* __restrict__ cw,
                      const float* __restrict__ cb, const float* __restrict__ pe,
                      const float* __restrict__ g, const float* __restrict__ bb,
                      float* __restrict__ z) {
    int tid = threadIdx.x;
    int w = tid >> 6, l = tid & 63;
    int t = blockIdx.x*4 + w;
    int lt = t & (LATN - 1);
    int b = t >> 9;
    const float* xb = x + (size_t)b * 1024;
    int p0 = 2 * lt;
    float xv[6];
    #pragma unroll
    for (int i = 0; i < 6; ++i) {
        int p = min(max(p0 - 2 + i, 0), 1023);
        xv[i] = xb[p];
    }
    float v[4]; float s = 0.f, q = 0.f;
    #pragma unroll
    for (int c = 0; c < 4; ++c) {
        int d = l + 64*c;
        float w0 = cw[d*5+0], w1 = cw[d*5+1], w2 = cw[d*5+2], w3 = cw[d*5+3], w4 = cw[d*5+4];
        float bv = cb[d];
        float h0 = bv + w0*xv[0] + w1*xv[1] + w2*xv[2] + w3*xv[3] + w4*xv[4];
        float h1 = bv + w0*xv[1] + w1*xv[2] + w2*xv[3] + w3*xv[4] + w4*xv[5];
        float pool = sqrtf(h0*h0 + h1*h1);
        float val = pool + pe[lt*DN + d];
        v[c] = val; s += val; q += val*val;
    }
    s = wave_sum(s); q = wave_sum(q);
    float mu = s * (1.0f/DN);
    float var = q * (1.0f/DN) - mu*mu;
    float rs = rsqrtf(var + 1e-5f);
    #pragma unroll
    for (int c = 0; c < 4; ++c) {
        int d = l + 64*c;
        z[(size_t)t*DN + d] = (v[c] - mu)*rs*g[d] + bb[d];
    }
}

// ---------------- pack projection weights: fp32 [out,in] -> bf16 B-frag ----------
__global__ void pack_proj(const float* __restrict__ wq, const float* __restrict__ wk,
                          const float* __restrict__ wv, const float* __restrict__ wo,
                          unsigned short* __restrict__ wp) {
    int mat = blockIdx.y;              // 0..7 : layer*4 + {q,k,v,o}
    int l0 = mat >> 2, which = mat & 3;
    const float* base = (which == 0) ? wq : (which == 1) ? wk : (which == 2) ? wv : wo;
    const float* W = base + l0*65536;
    int tid = blockIdx.x*256 + threadIdx.x;   // 0..8191
    int l = tid & 63, kk = (tid >> 6) & 7, nt = tid >> 9;
    const float* src = W + (size_t)(nt*16 + (l&15))*DN + kk*32 + (l>>4)*8;
    unsigned short o[8];
    #pragma unroll
    for (int j = 0; j < 8; ++j) o[j] = f2bf(src[j]);
    *(ulonglong2*)(wp + (size_t)mat*65536 + (size_t)tid*8) = *(ulonglong2*)o;
}

// ---------------- MFMA projection GEMM body. OM: 1=bf16 out, 2=bf16 vT ----------
template<int OM>
__device__ __forceinline__ void proj_body(const float* __restrict__ A,
                                          const unsigned short* __restrict__ wpm,
                                          const float* __restrict__ bias,
                                          void* __restrict__ outp, int t0, float oscale,
                                          unsigned short* ts) {
    int tid = threadIdx.x;
    #pragma unroll
    for (int i = 0; i < 16; ++i) {
        int f4 = i*256 + tid;
        int row = f4 >> 6, c4 = f4 & 63;
        float4 a = *(const float4*)&A[(size_t)(t0+row)*DN + c4*4];
        ushort4 o = { f2bf(a.x), f2bf(a.y), f2bf(a.z), f2bf(a.w) };
        *(ushort4*)&ts[row*264 + c4*4] = o;
    }
    __syncthreads();
    int w = tid >> 6, l = tid & 63;
    f32x4 acc[4][4];
    #pragma unroll
    for (int m = 0; m < 4; ++m)
        #pragma unroll
        for (int n = 0; n < 4; ++n) acc[m][n] = (f32x4){0.f,0.f,0.f,0.f};
    const bf16x8* wv = (const bf16x8*)wpm;
    #pragma unroll
    for (int kk = 0; kk < 8; ++kk) {
        bf16x8 af[4];
        #pragma unroll
        for (int m = 0; m < 4; ++m)
            af[m] = *(const bf16x8*)&ts[(m*16 + (l&15))*264 + kk*32 + (l>>4)*8];
        #pragma unroll
        for (int n = 0; n < 4; ++n) {
            bf16x8 bf = wv[((w*4 + n)*8 + kk)*64 + l];
            #pragma unroll
            for (int m = 0; m < 4; ++m)
                acc[m][n] = __builtin_amdgcn_mfma_f32_16x16x32_bf16(af[m], bf, acc[m][n], 0, 0, 0);
        }
    }
    #pragma unroll
    for (int n = 0; n < 4; ++n) {
        int col = w*64 + n*16 + (l&15);
        float bv2 = bias[col];
        #pragma unroll
        for (int m = 0; m < 4; ++m) {
            #pragma unroll
            for (int r = 0; r < 4; ++r) {
                int row = t0 + m*16 + (l>>4)*4 + r;
                float val = acc[m][n][r] + bv2;
                if (OM == 1)
                    ((unsigned short*)outp)[(size_t)row*DN + col] = f2bf(val * oscale);
                else
                    ((unsigned short*)outp)[(((size_t)(row>>9)*2 + (col>>7))*128 + (col&127))*512 + (row&511)] = f2bf(val);
            }
        }
    }
}

__global__ __launch_bounds__(256)
void proj_qkv(const float* __restrict__ z, const unsigned short* __restrict__ wp,
              const float* __restrict__ bq, const float* __restrict__ bk,
              const float* __restrict__ bv,
              unsigned short* __restrict__ qb, unsigned short* __restrict__ kb,
              unsigned short* __restrict__ vtb) {
    __shared__ unsigned short ts[64*264];
    int mat = blockIdx.y;
    if (mat == 0)      proj_body<1>(z, wp,          bq, qb,  blockIdx.x*64, 0.08838834764831844f, ts);
    else if (mat == 1) proj_body<1>(z, wp + 65536,  bk, kb,  blockIdx.x*64, 1.0f, ts);
    else               proj_body<2>(z, wp + 131072, bv, vtb, blockIdx.x*64, 1.0f, ts);
}

// ---------------- out-proj + residual + LN fused (writes z in place) ------------
__global__ __launch_bounds__(256)
void proj_o_ln(const float* __restrict__ A, const unsigned short* __restrict__ wpm,
               const float* __restrict__ bias, float* __restrict__ z,
               const float* __restrict__ lng, const float* __restrict__ lnb) {
    __shared__ unsigned short ts[64*264];
    __shared__ float wsum[4][64], wsq[4][64];
    int t0 = blockIdx.x * 64;
    int tid = threadIdx.x;
    #pragma unroll
    for (int i = 0; i < 16; ++i) {
        int f4 = i*256 + tid;
        int row = f4 >> 6, c4 = f4 & 63;
        float4 a = *(const float4*)&A[(size_t)(t0+row)*DN + c4*4];
        ushort4 o = { f2bf(a.x), f2bf(a.y), f2bf(a.z), f2bf(a.w) };
        *(ushort4*)&ts[row*264 + c4*4] = o;
    }
    __syncthreads();
    int w = tid >> 6, l = tid & 63, c = l & 15, g = l >> 4;
    f32x4 acc[4][4];
    #pragma unroll
    for (int m = 0; m < 4; ++m)
        #pragma unroll
        for (int n = 0; n < 4; ++n) acc[m][n] = (f32x4){0.f,0.f,0.f,0.f};
    const bf16x8* wv = (const bf16x8*)wpm;
    #pragma unroll
    for (int kk = 0; kk < 8; ++kk) {
        bf16x8 af[4];
        #pragma unroll
        for (int m = 0; m < 4; ++m)
            af[m] = *(const bf16x8*)&ts[(m*16 + c)*264 + kk*32 + g*8];
        #pragma unroll
        for (int n = 0; n < 4; ++n) {
            bf16x8 bf = wv[((w*4 + n)*8 + kk)*64 + l];
            #pragma unroll
            for (int m = 0; m < 4; ++m)
                acc[m][n] = __builtin_amdgcn_mfma_f32_16x16x32_bf16(af[m], bf, acc[m][n], 0, 0, 0);
        }
    }
    float vals[4][4][4];
    float sm[4][4], sq[4][4];
    #pragma unroll
    for (int m = 0; m < 4; ++m)
        #pragma unroll
        for (int r = 0; r < 4; ++r) { sm[m][r] = 0.f; sq[m][r] = 0.f; }
    #pragma unroll
    for (int n = 0; n < 4; ++n) {
        int col = w*64 + n*16 + c;
        float bv2 = bias[col];
        #pragma unroll
        for (int m = 0; m < 4; ++m)
            #pragma unroll
            for (int r = 0; r < 4; ++r) {
                int row = t0 + m*16 + g*4 + r;
                float v = acc[m][n][r] + bv2 + z[(size_t)row*DN + col];
                vals[m][n][r] = v;
                sm[m][r] += v; sq[m][r] += v*v;
            }
    }
    #pragma unroll
    for (int m = 0; m < 4; ++m)
        #pragma unroll
        for (int r = 0; r < 4; ++r) {
            #pragma unroll
            for (int off = 1; off <= 8; off <<= 1) {
                sm[m][r] += __shfl_xor(sm[m][r], off, 64);
                sq[m][r] += __shfl_xor(sq[m][r], off, 64);
            }
        }
    if (c == 0) {
        #pragma unroll
        for (int m = 0; m < 4; ++m)
            #pragma unroll
            for (int r = 0; r < 4; ++r) {
                wsum[w][m*16 + g*4 + r] = sm[m][r];
                wsq[w][m*16 + g*4 + r] = sq[m][r];
            }
    }
    __syncthreads();
    #pragma unroll
    for (int m = 0; m < 4; ++m)
        #pragma unroll
        for (int r = 0; r < 4; ++r) {
            int rl = m*16 + g*4 + r;
            float S = wsum[0][rl] + wsum[1][rl] + wsum[2][rl] + wsum[3][rl];
            float Q = wsq[0][rl] + wsq[1][rl] + wsq[2][rl] + wsq[3][rl];
            float mu = S * (1.0f/DN);
            float var = Q * (1.0f/DN) - mu*mu;
            float rs = rsqrtf(var + 1e-5f);
            int row = t0 + rl;
            #pragma unroll
            for (int n = 0; n < 4; ++n) {
                int col = w*64 + n*16 + c;
                z[(size_t)row*DN + col] = (vals[m][n][r] - mu)*rs*lng[col] + lnb[col];
            }
        }
}

// ---------------- MFMA attention: swapped QK^T (S^T), in-reg softmax, PV via LDS-P
__global__ __launch_bounds__(256)
void attn_mfma(const unsigned short* __restrict__ qb, const unsigned short* __restrict__ kb,
               const unsigned short* __restrict__ vtb, float* __restrict__ a) {
    int blk = blockIdx.x;
    int xcd = blk & 7, idx = blk >> 3;
    int bh = xcd*2 + (idx & 1);        // 2 bh per XCD -> 1 MB L2 working set
    int qt = idx >> 1;
    int b = bh >> 1, h = bh & 1;
    int q0 = qt * 32;
    int tid = threadIdx.x;
    int w = tid >> 6, l = tid & 63;
    int c = l & 15, g = l >> 4;

    __shared__ __align__(16) unsigned short p_lds[32*512];  // [q][key] bf16, XOR-swizzled
    __shared__ float smax[4][2][16];
    __shared__ float ssum[4][2][16];

    bf16x8 qf_[2][4];
    #pragma unroll
    for (int qf = 0; qf < 2; ++qf)
        #pragma unroll
        for (int kk = 0; kk < 4; ++kk)
            qf_[qf][kk] = *(const bf16x8*)&qb[((size_t)(b*LATN + q0 + qf*16 + c))*DN + h*DKN + kk*32 + g*8];

    f32x4 st[8][2];
    #pragma unroll
    for (int f = 0; f < 8; ++f) { st[f][0] = (f32x4){0,0,0,0}; st[f][1] = (f32x4){0,0,0,0}; }
    #pragma unroll
    for (int f = 0; f < 8; ++f) {
        int kbase = w*128 + f*16;
        bf16x8 kf[4];
        #pragma unroll
        for (int kk = 0; kk < 4; ++kk)
            kf[kk] = *(const bf16x8*)&kb[((size_t)(b*LATN + kbase + c))*DN + h*DKN + kk*32 + g*8];
        #pragma unroll
        for (int kk = 0; kk < 4; ++kk) {
            st[f][0] = __builtin_amdgcn_mfma_f32_16x16x32_bf16(kf[kk], qf_[0][kk], st[f][0], 0, 0, 0);
            st[f][1] = __builtin_amdgcn_mfma_f32_16x16x32_bf16(kf[kk], qf_[1][kk], st[f][1], 0, 0, 0);
        }
    }

    float gmax[2], ginv[2];
    #pragma unroll
    for (int qf = 0; qf < 2; ++qf) {
        float m = -1e30f;
        #pragma unroll
        for (int f = 0; f < 8; ++f)
            #pragma unroll
            for (int r = 0; r < 4; ++r) m = fmaxf(m, st[f][qf][r]);
        m = fmaxf(m, __shfl_xor(m, 16, 64));
        m = fmaxf(m, __shfl_xor(m, 32, 64));
        if (l < 16) smax[w][qf][l] = m;
    }
    __syncthreads();
    #pragma unroll
    for (int qf = 0; qf < 2; ++qf)
        gmax[qf] = fmaxf(fmaxf(smax[0][qf][c], smax[1][qf][c]),
                         fmaxf(smax[2][qf][c], smax[3][qf][c]));
    #pragma unroll
    for (int qf = 0; qf < 2; ++qf) {
        float s = 0.f;
        #pragma unroll
        for (int f = 0; f < 8; ++f)
            #pragma unroll
            for (int r = 0; r < 4; ++r) {
                float e = __expf(st[f][qf][r] - gmax[qf]);
                st[f][qf][r] = e; s += e;
            }
        s += __shfl_xor(s, 16, 64);
        s += __shfl_xor(s, 32, 64);
        if (l < 16) ssum[w][qf][l] = s;
    }
    __syncthreads();
    #pragma unroll
    for (int qf = 0; qf < 2; ++qf)
        ginv[qf] = 1.0f / (ssum[0][qf][c] + ssum[1][qf][c] + ssum[2][qf][c] + ssum[3][qf][c]);

    #pragma unroll
    for (int qf = 0; qf < 2; ++qf) {
        int q_ = qf*16 + c;
        int rowb = q_ * 1024;
        int swz = (q_ & 7) << 4;
        float iv = ginv[qf];
        #pragma unroll
        for (int f = 0; f < 8; ++f) {
            unsigned int lo = (unsigned int)f2bf(st[f][qf][0]*iv) |
                              ((unsigned int)f2bf(st[f][qf][1]*iv) << 16);
            unsigned int hi = (unsigned int)f2bf(st[f][qf][2]*iv) |
                              ((unsigned int)f2bf(st[f][qf][3]*iv) << 16);
            int key0 = w*128 + f*16 + g*4;
            *(unsigned long long*)((char*)p_lds + rowb + ((key0*2) ^ swz)) =
                (unsigned long long)lo | ((unsigned long long)hi << 32);
        }
    }
    __syncthreads();

    f32x4 o[2][2];
    o[0][0] = (f32x4){0,0,0,0}; o[0][1] = (f32x4){0,0,0,0};
    o[1][0] = (f32x4){0,0,0,0}; o[1][1] = (f32x4){0,0,0,0};
    #pragma unroll
    for (int kk = 0; kk < 16; ++kk) {
        bf16x8 pb[2];
        #pragma unroll
        for (int qf = 0; qf < 2; ++qf) {
            int q_ = qf*16 + c;
            pb[qf] = *(const bf16x8*)((const char*)p_lds + q_*1024 +
                                      (((kk*32 + g*8)*2) ^ ((q_&7)<<4)));
        }
        bf16x8 va[2];
        #pragma unroll
        for (int m = 0; m < 2; ++m)
            va[m] = *(const bf16x8*)&vtb[((size_t)(bh*128 + w*32 + m*16 + c))*512 + kk*32 + g*8];
        #pragma unroll
        for (int m = 0; m < 2; ++m) {
            o[m][0] = __builtin_amdgcn_mfma_f32_16x16x32_bf16(va[m], pb[0], o[m][0], 0, 0, 0);
            o[m][1] = __builtin_amdgcn_mfma_f32_16x16x32_bf16(va[m], pb[1], o[m][1], 0, 0, 0);
        }
    }
    #pragma unroll
    for (int m = 0; m < 2; ++m)
        #pragma unroll
        for (int qf = 0; qf < 2; ++qf)
            #pragma unroll
            for (int r = 0; r < 4; ++r) {
                int d = w*32 + m*16 + g*4 + r;
                a[((size_t)(b*LATN + q0 + qf*16 + c))*DN + h*DKN + d] = o[m][qf][r];
            }
}

// ---------------- router: 32 tokens/block, block-aggregated padded atomics ----
#define RTOK 32
__global__ __launch_bounds__(512)
void router_kernel(const float* __restrict__ z, const float* __restrict__ rw,
                   const float* __restrict__ rb, float* __restrict__ rmaxv,
                   float* __restrict__ rprob_p, int* __restrict__ ec_p,
                   int* __restrict__ elist) {
    __shared__ float rws[NEXP*DN];
    __shared__ float sprob[NEXP];
    __shared__ int lcnt[NEXP], lbase[NEXP];
    __shared__ int lrank[RTOK];
    __shared__ int lam[RTOK];
    int tid = threadIdx.x;
    for (int i = tid; i < NEXP*DN; i += 512) rws[i] = rw[i];
    if (tid < NEXP) { sprob[tid] = 0.f; lcnt[tid] = 0; }
    __syncthreads();
    int g = tid >> 4, j = tid & 15;
    int t = blockIdx.x * RTOK + g;
    const float4* z4 = (const float4*)&z[(size_t)t*DN + j*16];
    const float4* rws4 = (const float4*)rws;
    float acc[NEXP];
    #pragma unroll
    for (int e = 0; e < NEXP; ++e) acc[e] = 0.f;
    int r0 = (j >> 1) & 3;
    #pragma unroll
    for (int kq = 0; kq < 4; ++kq) {
        int k4 = (kq + r0) & 3;
        float4 zv = z4[k4];
        #pragma unroll
        for (int e = 0; e < NEXP; ++e)
            acc[e] += dot4(zv, rws4[e*64 + j*4 + k4]);
    }
    #pragma unroll
    for (int e = 0; e < NEXP; ++e) {
        acc[e] += __shfl_xor(acc[e], 1, 64);
        acc[e] += __shfl_xor(acc[e], 2, 64);
        acc[e] += __shfl_xor(acc[e], 4, 64);
        acc[e] += __shfl_xor(acc[e], 8, 64);
    }
    if (j == 0) {
        float lg[NEXP];
        float m = acc[0] + rb[0]; int am = 0;
        lg[0] = m;
        #pragma unroll
        for (int e = 1; e < NEXP; ++e) {
            lg[e] = acc[e] + rb[e];
            if (lg[e] > m) { m = lg[e]; am = e; }
        }
        float p[NEXP], s = 0.f;
        #pragma unroll
        for (int e = 0; e < NEXP; ++e) { p[e] = expf(lg[e] - m); s += p[e]; }
        float inv = 1.0f / s;
        rmaxv[t] = p[am] * inv;
        lam[g] = am;
        lrank[g] = atomicAdd(&lcnt[am], 1);             // LDS atomic
        #pragma unroll
        for (int e = 0; e < NEXP; ++e) atomicAdd(&sprob[e], p[e] * inv);  // LDS atomic
    }
    __syncthreads();
    if (tid < NEXP) {
        lbase[tid] = atomicAdd(&ec_p[tid*16], lcnt[tid]);   // padded: 1 line/expert
        atomicAdd(&rprob_p[tid*16], sprob[tid]);            // padded: 1 line/expert
    }
    __syncthreads();
    if (j == 0)
        elist[lam[g]*TTOT + lbase[lam[g]] + lrank[g]] = t;
}

// ---------------- pack expert weights (merged): fp32 -> bf16 B-frag --------------
__global__ void pack_experts(const float* __restrict__ w1l, const float* __restrict__ w2l,
                             unsigned short* __restrict__ w1p, unsigned short* __restrict__ w2p) {
    int tid = blockIdx.x*256 + threadIdx.x;   // 327680 per matrix set
    unsigned short o[8];
    if (blockIdx.y == 0) {
        int l = tid & 63, kk = (tid >> 6) & 7, nt = (tid >> 9) & 63, e = tid >> 15;
        const float* src = w1l + (size_t)e*262144 + (size_t)(kk*32 + (l>>4)*8)*DFFN + nt*16 + (l&15);
        #pragma unroll
        for (int j = 0; j < 8; ++j) o[j] = f2bf(src[(size_t)j*DFFN]);
        *(ulonglong2*)(w1p + (size_t)tid*8) = *(ulonglong2*)o;
    } else {
        int l = tid & 63, kk = (tid >> 6) & 31, nt = (tid >> 11) & 15, e = tid >> 15;
        const float* src = w2l + (size_t)e*262144 + (size_t)(kk*32 + (l>>4)*8)*DN + nt*16 + (l&15);
        #pragma unroll
        for (int j = 0; j < 8; ++j) o[j] = f2bf(src[(size_t)j*DN]);
        *(ulonglong2*)(w2p + (size_t)tid*8) = *(ulonglong2*)o;
    }
}

// ---------------- MoE: TM=16, 2D grid, 8 waves/block (round-14 config) -----------
#define TM 16
__global__ __launch_bounds__(512)
void moe_kernel(float* __restrict__ z, const int* __restrict__ elist,
                const int* __restrict__ ec_p, const float* __restrict__ rmaxv,
                const unsigned short* __restrict__ w1p, const float* __restrict__ b1,
                const unsigned short* __restrict__ w2p, const float* __restrict__ b2,
                const float* __restrict__ g, const float* __restrict__ bb) {
    int e = blockIdx.y;
    int cnt = ec_p[e*16];
    int base = blockIdx.x * TM;
    if (base >= cnt) return;
    int n = min(TM, cnt - base);

    __shared__ __align__(16) unsigned short ts[16*264];
    __shared__ __align__(16) unsigned short hbuf[16*1032];
    __shared__ __align__(16) float ybuf[16*260];
    __shared__ int toks[16];
    __shared__ float rm[16];

    int tid = threadIdx.x;
    int w = tid >> 6, l = tid & 63, c = l & 15, gq = l >> 4;
    if (tid < 16) {
        int tt = (tid < n) ? elist[e*TTOT + base + tid] : 0;
        toks[tid] = tt;
        rm[tid] = rmaxv[tt];
    }
    __syncthreads();
    {
        int half = tid >> 8, colx = tid & 255;
        #pragma unroll
        for (int m = 0; m < 8; ++m)
            ts[(half*8 + m)*264 + colx] = f2bf(z[(size_t)toks[half*8 + m]*DN + colx]);
    }
    __syncthreads();

    const bf16x8* w1v = (const bf16x8*)w1p;
    const float* b1e = b1 + e*DFFN;
    f32x4 acc[8];
    #pragma unroll
    for (int i = 0; i < 8; ++i) acc[i] = (f32x4){0.f,0.f,0.f,0.f};
    #pragma unroll
    for (int kk = 0; kk < 8; ++kk) {
        bf16x8 a = *(const bf16x8*)(ts + c*264 + kk*32 + gq*8);
        const bf16x8* wbp = w1v + (((size_t)e*64 + w*8)*8 + kk)*64 + l;
        #pragma unroll
        for (int nt2 = 0; nt2 < 8; ++nt2)
            acc[nt2] = __builtin_amdgcn_mfma_f32_16x16x32_bf16(a, wbp[nt2*512], acc[nt2], 0, 0, 0);
    }
    #pragma unroll
    for (int nt2 = 0; nt2 < 8; ++nt2) {
        int col = w*128 + nt2*16 + c;
        float bv = b1e[col];
        #pragma unroll
        for (int r = 0; r < 4; ++r) {
            int row = gq*4 + r;
            hbuf[row*1032 + col] = f2bf(fmaxf(acc[nt2][r] + bv, 0.f));
        }
    }
    __syncthreads();

    const bf16x8* w2v = (const bf16x8*)w2p;
    const float* b2e = b2 + e*DN;
    f32x4 acc2[2];
    acc2[0] = (f32x4){0.f,0.f,0.f,0.f};
    acc2[1] = (f32x4){0.f,0.f,0.f,0.f};
    for (int kk = 0; kk < 32; ++kk) {
        bf16x8 a = *(const bf16x8*)(hbuf + c*1032 + kk*32 + gq*8);
        const bf16x8* wbp = w2v + (((size_t)e*16 + w*2)*32 + kk)*64 + l;
        acc2[0] = __builtin_amdgcn_mfma_f32_16x16x32_bf16(a, wbp[0], acc2[0], 0, 0, 0);
        acc2[1] = __builtin_amdgcn_mfma_f32_16x16x32_bf16(a, wbp[2048], acc2[1], 0, 0, 0);
    }
    #pragma unroll
    for (int nt2 = 0; nt2 < 2; ++nt2) {
        int col = w*32 + nt2*16 + c;
        float bv = b2e[col];
        #pragma unroll
        for (int r = 0; r < 4; ++r) {
            int row = gq*4 + r;
            ybuf[row*260 + col] = (acc2[nt2][r] + bv) * rm[row];
        }
    }
    __syncthreads();

    #pragma unroll
    for (int rr = 0; rr < 2; ++rr) {
        int row = w*2 + rr;
        if (row < n) {
            int t = toks[row];
            float v[4];
            #pragma unroll
            for (int cc = 0; cc < 4; ++cc)
                v[cc] = ybuf[row*260 + l + 64*cc] + z[(size_t)t*DN + l + 64*cc];
            float s = wave_sum(v[0]+v[1]+v[2]+v[3]);
            float mu = s * (1.0f/DN);
            float s2 = 0.f;
            #pragma unroll
            for (int cc = 0; cc < 4; ++cc) { v[cc] -= mu; s2 += v[cc]*v[cc]; }
            s2 = wave_sum(s2);
            float rs = rsqrtf(s2 * (1.0f/DN) + 1e-5f);
            #pragma unroll
            for (int cc = 0; cc < 4; ++cc) {
                int col = l + 64*cc;
                z[(size_t)t*DN + col] = v[cc]*rs*g[col] + bb[col];
            }
        }
    }
}

// ---------------- pack tail weights: deconv taps + lin1 (merged) -----------------
__global__ void pack_tail(const float* __restrict__ w, const float* __restrict__ l1w,
                          unsigned short* __restrict__ wdp, unsigned short* __restrict__ wl1) {
    int bid = blockIdx.x;
    unsigned short o[8];
    if (bid < 128) {
        int tid = bid*256 + threadIdx.x;   // 32768
        int l = tid & 63, kk = (tid >> 6) & 7, nt = (tid >> 9) & 15, tap = tid >> 13;
        int dout = nt*16 + (l&15);
        int din0 = kk*32 + (l>>4)*8;
        #pragma unroll
        for (int j = 0; j < 8; ++j)
            o[j] = f2bf(w[((size_t)(din0 + j)*DN + dout)*4 + tap]);
        *(ulonglong2*)(wdp + (size_t)tid*8) = *(ulonglong2*)o;
    } else {
        int tid = (bid - 128)*256 + threadIdx.x;   // 4096
        int l = tid & 63, kk = (tid >> 6) & 7, nt = tid >> 9;
        const float* src = l1w + (size_t)(nt*16 + (l&15))*DN + kk*32 + (l>>4)*8;
        #pragma unroll
        for (int j = 0; j < 8; ++j) o[j] = f2bf(src[j]);
        *(ulonglong2*)(wl1 + (size_t)tid*8) = *(ulonglong2*)o;
    }
}

// ---------------- fused deconv (MFMA) + head, 32 u-rows/block (grid 256) ---------
__global__ __launch_bounds__(256)
void deconv_head(const float* __restrict__ z, const unsigned short* __restrict__ wdp,
                 const float* __restrict__ db, const unsigned short* __restrict__ wl1,
                 const float* __restrict__ hb1, const float* __restrict__ hw2,
                 const float* __restrict__ hb2, float* __restrict__ out) {
    int blk = blockIdx.x;              // 256 blocks
    int b = blk >> 5, lt = blk & 31;
    int l0 = lt * 16;
    __shared__ __align__(16) unsigned short zs[18*264];
    __shared__ __align__(16) unsigned short us[32*264];
    __shared__ float part[4][32];
    int tid = threadIdx.x;
    // ---- stage z rows [l0-1, l0+17): 18 rows x 256 cols
    for (int i = tid; i < 18*64; i += 256) {
        int row = i >> 6, c4 = i & 63;
        int l = l0 - 1 + row;
        float4 a = (l >= 0 && l < LATN)
            ? *(const float4*)&z[((size_t)b*LATN + l)*DN + c4*4]
            : make_float4(0.f, 0.f, 0.f, 0.f);
        ushort4 o = { f2bf(a.x), f2bf(a.y), f2bf(a.z), f2bf(a.w) };
        *(ushort4*)&zs[row*264 + c4*4] = o;
    }
    __syncthreads();
    int w = tid >> 6, l = tid & 63;
    int c = l & 15, g = l >> 4;
    // ---- deconv MFMA: one 16-row A tile; wave w owns 64 output cols
    f32x4 acce[4], acco[4];
    #pragma unroll
    for (int n = 0; n < 4; ++n) {
        acce[n] = (f32x4){0.f,0.f,0.f,0.f};
        acco[n] = (f32x4){0.f,0.f,0.f,0.f};
    }
    const bf16x8* wdv = (const bf16x8*)wdp;
    #pragma unroll
    for (int kk = 0; kk < 8; ++kk) {
        int rb = c*264 + kk*32 + g*8;
        bf16x8 a0 = *(const bf16x8*)&zs[rb];          // z[l0+c-1]
        bf16x8 a1 = *(const bf16x8*)&zs[rb + 264];    // z[l0+c]
        bf16x8 a2 = *(const bf16x8*)&zs[rb + 528];    // z[l0+c+1]
        #pragma unroll
        for (int n = 0; n < 4; ++n) {
            int nt = w*4 + n;
            bf16x8 bt0 = wdv[((0*16 + nt)*8 + kk)*64 + l];
            bf16x8 bt1 = wdv[((1*16 + nt)*8 + kk)*64 + l];
            bf16x8 bt2 = wdv[((2*16 + nt)*8 + kk)*64 + l];
            bf16x8 bt3 = wdv[((3*16 + nt)*8 + kk)*64 + l];
            acco[n] = __builtin_amdgcn_mfma_f32_16x16x32_bf16(a2, bt0, acco[n], 0, 0, 0);
            acce[n] = __builtin_amdgcn_mfma_f32_16x16x32_bf16(a1, bt1, acce[n], 0, 0, 0);
            acco[n] = __builtin_amdgcn_mfma_f32_16x16x32_bf16(a1, bt2, acco[n], 0, 0, 0);
            acce[n] = __builtin_amdgcn_mfma_f32_16x16x32_bf16(a0, bt3, acce[n], 0, 0, 0);
        }
    }
    // ---- u tile (32 rows x 256 cols) -> bf16 LDS (with deconv bias)
    #pragma unroll
    for (int n = 0; n < 4; ++n) {
        int col = (w*4 + n)*16 + c;
        float bv = db[col];
        #pragma unroll
        for (int r = 0; r < 4; ++r) {
            int rt = g*4 + r;                  // u-row pair index in [0,16)
            us[(2*rt)*264 + col]     = f2bf(acce[n][r] + bv);
            us[(2*rt + 1)*264 + col] = f2bf(acco[n][r] + bv);
        }
    }
    __syncthreads();
    // ---- head: lin1 MFMA (32 rows = 2 m-tiles) + tanh*lin2 + reduce
    f32x4 hacc[2][2];
    #pragma unroll
    for (int m = 0; m < 2; ++m) { hacc[m][0] = (f32x4){0.f,0.f,0.f,0.f}; hacc[m][1] = (f32x4){0.f,0.f,0.f,0.f}; }
    const bf16x8* wv1 = (const bf16x8*)wl1;
    #pragma unroll
    for (int kk = 0; kk < 8; ++kk) {
        bf16x8 af[2];
        #pragma unroll
        for (int m = 0; m < 2; ++m)
            af[m] = *(const bf16x8*)&us[(m*16 + c)*264 + kk*32 + g*8];
        #pragma unroll
        for (int n = 0; n < 2; ++n) {
            bf16x8 bf = wv1[((w*2 + n)*8 + kk)*64 + l];
            #pragma unroll
            for (int m = 0; m < 2; ++m)
                hacc[m][n] = __builtin_amdgcn_mfma_f32_16x16x32_bf16(af[m], bf, hacc[m][n], 0, 0, 0);
        }
    }
    float pm[2][4];
    #pragma unroll
    for (int m = 0; m < 2; ++m)
        #pragma unroll
        for (int r = 0; r < 4; ++r) pm[m][r] = 0.f;
    #pragma unroll
    for (int n = 0; n < 2; ++n) {
        int col = (w*2 + n)*16 + c;
        float bb1 = hb1[col], ww2 = hw2[col];
        #pragma unroll
        for (int m = 0; m < 2; ++m)
            #pragma unroll
            for (int r = 0; r < 4; ++r)
                pm[m][r] += tanhf(hacc[m][n][r] + bb1) * ww2;
    }
    #pragma unroll
    for (int off = 1; off <= 8; off <<= 1)
        #pragma unroll
        for (int m = 0; m < 2; ++m)
            #pragma unroll
            for (int r = 0; r < 4; ++r)
                pm[m][r] += __shfl_xor(pm[m][r], off, 64);
    if (c == 0) {
        #pragma unroll
        for (int m = 0; m < 2; ++m)
            #pragma unroll
            for (int r = 0; r < 4; ++r)
                part[w][m*16 + g*4 + r] = pm[m][r];
    }
    __syncthreads();
    if (tid < 32)
        out[blk*32 + tid] = part[0][tid] + part[1][tid] + part[2][tid] + part[3][tid] + hb2[0];
}

// ---------------- loss ----------------
__global__ void loss_kernel(const int* __restrict__ ec_p, const float* __restrict__ rprob_p,
                            float* __restrict__ out) {
    if (threadIdx.x == 0) {
        float s = 0;
        for (int l = 0; l < 2; ++l)
            for (int e = 0; e < NEXP; ++e)
                s += (float)ec_p[l*160 + e*16] * rprob_p[l*160 + e*16];
        out[8192] = 10.0f * s / (4096.0f * 4096.0f);
    }
}

extern "C" void kernel_launch(void* const* d_in, const int* in_sizes, int n_in,
                              void* d_out, int out_size, void* d_ws, size_t ws_size,
                              hipStream_t stream) {
    const float* x        = (const float*)d_in[0];
    const float* conv_w   = (const float*)d_in[1];
    const float* conv_b   = (const float*)d_in[2];
    const float* pe       = (const float*)d_in[3];
    const float* ln0_g    = (const float*)d_in[4];
    const float* ln0_b    = (const float*)d_in[5];
    const float* wq       = (const float*)d_in[6];
    const float* bq       = (const float*)d_in[7];
    const float* wk       = (const float*)d_in[8];
    const float* bk       = (const float*)d_in[9];
    const float* wv       = (const float*)d_in[10];
    const float* bv       = (const float*)d_in[11];
    const float* wo       = (const float*)d_in[12];
    const float* bo       = (const float*)d_in[13];
    const float* ln1_g    = (const float*)d_in[14];
    const float* ln1_b    = (const float*)d_in[15];
    const float* ln2_g    = (const float*)d_in[16];
    const float* ln2_b    = (const float*)d_in[17];
    const float* router_w = (const float*)d_in[18];
    const float* router_b = (const float*)d_in[19];
    const float* e_w1     = (const float*)d_in[20];
    const float* e_b1     = (const float*)d_in[21];
    const float* e_w2     = (const float*)d_in[22];
    const float* e_b2     = (const float*)d_in[23];
    const float* deconv_w = (const float*)d_in[24];
    const float* deconv_b = (const float*)d_in[25];
    const float* lin1_w   = (const float*)d_in[26];
    const float* lin1_b   = (const float*)d_in[27];
    const float* lin2_w   = (const float*)d_in[28];
    const float* lin2_b   = (const float*)d_in[29];

    float* ws = (float*)d_ws;
    const size_t M = 1048576;
    float* z    = ws;
    unsigned short* qb  = (unsigned short*)(ws + 1*M);   // bf16 Q (pre-scaled)
    unsigned short* kb  = (unsigned short*)(ws + 2*M);   // bf16 K
    unsigned short* vtb = (unsigned short*)(ws + 3*M);   // bf16 V^T [bh][d][512]
    float* a    = ws + 4*M;
    float* rmax = ws + 6*M;
    float* rprob_p = rmax + 4096;             // 320 floats (16-stride padded)
    int* ec_p   = (int*)(rprob_p + 320);      // 320 ints (16-stride padded)
    int* elist  = ec_p + 320;                 // 2*10*4096
    unsigned short* wproj = (unsigned short*)(ws + 6*M + 98304);  // 8 x 65536 bf16 (1 MB)
    unsigned short* w1p = (unsigned short*)(ws + 1*M);  // per-layer packed over qb+kb (dead)
    unsigned short* w2p = (unsigned short*)(ws + 3*M);  // per-layer packed over vtb+a (dead)
    unsigned short* wdp = (unsigned short*)(ws + 3*M);
    unsigned short* wl1 = (unsigned short*)(ws + 3*M + 131072 + 64);
    float* out  = (float*)d_out;

    zero_kernel<<<1, 512, 0, stream>>>(rprob_p, ec_p);
    {
        dim3 pg(32, 8);
        pack_proj<<<pg, 256, 0, stream>>>(wq, wk, wv, wo, wproj);
    }
    tokenizer_kernel<<<1024, 256, 0, stream>>>(x, conv_w, conv_b, pe, ln0_g, ln0_b, z);

    for (int l = 0; l < 2; ++l) {
        const unsigned short* wpl = wproj + (size_t)l*4*65536;
        dim3 qkvg(64, 3);
        proj_qkv<<<qkvg, 256, 0, stream>>>(z, wpl, bq + l*256, bk + l*256, bv + l*256,
                                           qb, kb, vtb);
        attn_mfma<<<256, 256, 0, stream>>>(qb, kb, vtb, a);
        proj_o_ln<<<64, 256, 0, stream>>>(a, wpl + 3*65536, bo + l*256, z,
                                          ln1_g + l*256, ln1_b + l*256);
        router_kernel<<<TTOT/RTOK, 512, 0, stream>>>(z, router_w + l*2560, router_b + l*10,
                                                     rmax, rprob_p + l*160, ec_p + l*160,
                                                     elist + l*10*TTOT);
        {
            dim3 pkg(1280, 2);
            pack_experts<<<pkg, 256, 0, stream>>>(e_w1 + (size_t)l*2621440,
                                                  e_w2 + (size_t)l*2621440, w1p, w2p);
        }
        dim3 mg(TTOT/TM, NEXP);
        moe_kernel<<<mg, 512, 0, stream>>>(z, elist + l*10*TTOT, ec_p + l*160, rmax,
                                           w1p, e_b1 + l*10240,
                                           w2p, e_b2 + l*2560,
                                           ln2_g + l*256, ln2_b + l*256);
    }

    pack_tail<<<144, 256, 0, stream>>>(deconv_w, lin1_w, wdp, wl1);
    deconv_head<<<256, 256, 0, stream>>>(z, wdp, deconv_b, wl1,
                                         lin1_b, lin2_w, lin2_b, out);
    loss_kernel<<<1, 64, 0, stream>>>(ec_p, rprob_p, out);
}